// Round 13
// baseline (236.791 us; speedup 1.0000x reference)
//
#include <hip/hip_runtime.h>

#define B_ 32
#define S_ 64
#define H_ 300
#define H2_ 600
#define L_ 20
#define ROW_ 160                    // 8 pieces * 20
#define OUTQ_OFF ((size_t)B_ * S_ * ROW_)
#define NEG_INF -3.402823466e38f

#define NB_MP 1280                  // 64 bd * 20 l   (dispatched first)
#define NB_W 188                    // 48000 / 256 rounded up
#define NB_COS 1024                 // 64 bd * 16 pg (4 p-rows each)

typedef __attribute__((ext_vector_type(8))) _Float16 half8v;   // 8 f16 = 4 VGPRs
typedef __attribute__((ext_vector_type(4))) _Float16 half4v;   // 4 f16 = 8 B
typedef __attribute__((ext_vector_type(4))) float float4v;
typedef __attribute__((ext_vector_type(2))) float float2v;

// ---------------- cos block: (bd, pg) -> 4 p-rows x 64 q, norms in-block.
// r12-verified body; inner loop accumulators packed to float4 (v_pk_fma_f32,
// 2x fewer VALU insts). Reassociation only (4 fp32 partials vs serial sum).
struct CosS {                       // 19008 B
  float xq[S_][65];                 // stride 65: 2-way scalar reads (free)
  float xp[4][68];                  // 272 B rows, 16-B aligned, broadcast b128
  float qn_l[S_];
  float cp[4][S_];
};

__device__ __forceinline__ void cos_body(char* smem, int bid,
                                         const float* __restrict__ P,
                                         const float* __restrict__ Q,
                                         float* __restrict__ cosM,
                                         float* __restrict__ sumpart,
                                         float* __restrict__ sum_q) {
  CosS& S = *(CosS*)smem;
  // XCD swizzle: bd = (bid&7) + 8*((bid>>3)&7); pg = bid>>6  (bijective 8x8x16)
  int x = bid & 7, j = bid >> 3;
  int bd = x + 8 * (j & 7);
  int pg = bid >> 6;
  int b = bd >> 1, dir = bd & 1;
  int t = threadIdx.x;
  int q = t & 63, pr = t >> 6;
  const float* Pb = P + (size_t)b * S_ * H2_ + dir * H_;
  const float* Qb = Q + (size_t)b * S_ * H2_ + dir * H_;
  float4v dotv = {0.f, 0.f, 0.f, 0.f};
  float4v npv  = {0.f, 0.f, 0.f, 0.f};
  float4v nqv  = {0.f, 0.f, 0.f, 0.f};
  for (int c0 = 0; c0 < H_; c0 += 64) {          // 5 chunks (last zero-padded)
    __syncthreads();
#pragma unroll
    for (int jj = 0; jj < 4; ++jj) {             // 64 rows x 16 groups static
      int idx = t + 256 * jj;
      int s = idx >> 4, g = idx & 15;
      int h = c0 + 4 * g;
      float4v v = {0.f, 0.f, 0.f, 0.f};
      if (h < 297) v = *(const float4v*)&Qb[(size_t)s * H2_ + h];
      S.xq[s][4 * g + 0] = v.x; S.xq[s][4 * g + 1] = v.y;
      S.xq[s][4 * g + 2] = v.z; S.xq[s][4 * g + 3] = v.w;
    }
    if (t < 64) {                                // 4 rows x 16 groups static
      int s = t >> 4, g = t & 15;
      int h = c0 + 4 * g;
      float4v v = {0.f, 0.f, 0.f, 0.f};
      if (h < 297) v = *(const float4v*)&Pb[(size_t)(pg * 4 + s) * H2_ + h];
      *(float4v*)&S.xp[s][4 * g] = v;
    }
    __syncthreads();
    for (int hh = 0; hh < 64; hh += 4) {
      float4v av = *(const float4v*)&S.xp[pr][hh];       // wave-broadcast (free)
      float4v qv = {S.xq[q][hh + 0], S.xq[q][hh + 1],
                    S.xq[q][hh + 2], S.xq[q][hh + 3]};
      dotv = av * qv + dotv;                             // 2x v_pk_fma_f32
      npv  = av * av + npv;
      if (pr == 0) nqv = qv * qv + nqv;                  // wave-uniform branch
    }
  }
  if (pr == 0) {
    float nq2 = (nqv.x + nqv.y) + (nqv.z + nqv.w);
    S.qn_l[q] = sqrtf(nq2);
  }
  __syncthreads();
  float dot = (dotv.x + dotv.y) + (dotv.z + dotv.w);
  float np2 = (npv.x + npv.y) + (npv.z + npv.w);
  float pn = sqrtf(np2);                                 // uniform per wave
  float c = dot / (pn * S.qn_l[q]);
  int p = pg * 4 + pr;
  cosM[(size_t)bd * S_ * S_ + (size_t)p * S_ + q] = c;
  float rs = c;
#pragma unroll
  for (int m = 1; m < 64; m <<= 1) rs += __shfl_xor(rs, m);
  if (q == 0) sum_q[bd * S_ + p] = rs;
  S.cp[pr][q] = c;
  __syncthreads();
  if (t < S_)
    sumpart[((size_t)bd * 16 + pg) * S_ + t] =
        S.cp[0][t] + S.cp[1][t] + S.cp[2][t] + S.cp[3][t];
}

// ---------------- maxpool block (byte-identical to r12-verified version)
#define HP 72                       // padded fp16 row: 144 B, 16-B aligned f16x8 groups
struct MaxpoolS {                   // 21168 B
  _Float16 ph[S_][HP];
  _Float16 qh[S_][HP];
  float w1s[H_];
  float pn2[S_], qn2[S_];
  float colp[4][S_];
};

__device__ __forceinline__ void maxpool_body(char* smem, int bid,
                                             const float* __restrict__ P,
                                             const float* __restrict__ Q,
                                             const float* __restrict__ Wf,
                                             float* __restrict__ out) {
  MaxpoolS& S = *(MaxpoolS*)smem;
  // XCD swizzle: bd = (bid&7) + 8*((bid>>3)&7); l = bid>>6
  int x = bid & 7, j = bid >> 3;
  int bd = x + 8 * (j & 7);
  int l = j >> 3;
  int b = bd >> 1, dir = bd & 1;
  int t = threadIdx.x;
  int w = t >> 6, lane = t & 63, quad = lane >> 4, col = lane & 15;
  const float* wg = Wf + (size_t)(2 + dir) * L_ * H_ + (size_t)l * H_;
  if (t < 75) {
    float4v v = *(const float4v*)&wg[4 * t];
    float4v a = {fabsf(v.x), fabsf(v.y), fabsf(v.z), fabsf(v.w)};
    *(float4v*)&S.w1s[4 * t] = a;
  }
  const float* Pb = P + (size_t)b * S_ * H2_ + dir * H_;
  const float* Qb = Q + (size_t)b * S_ * H2_ + dir * H_;
  float4v acc[4];
#pragma unroll
  for (int qt = 0; qt < 4; ++qt) acc[qt] = (float4v){0.f, 0.f, 0.f, 0.f};
  float np2a[4] = {0.f, 0.f, 0.f, 0.f};
  float nq2a[4] = {0.f, 0.f, 0.f, 0.f};
  for (int h0 = 0; h0 < H_; h0 += 64) {          // 5 chunks (last zero-padded)
    __syncthreads();
#pragma unroll
    for (int jj = 0; jj < 4; ++jj) {             // float4 staging: 4 iters/chunk
      int idx = t + 256 * jj;
      int s = idx >> 4, c4 = idx & 15;
      int h = h0 + 4 * c4;
      float4v pv = {0.f, 0.f, 0.f, 0.f}, qv = {0.f, 0.f, 0.f, 0.f};
      if (h < 297) {                             // full group valid (h+3 <= 299)
        float4v wv = *(const float4v*)&S.w1s[h];
        float4v p4 = *(const float4v*)&Pb[(size_t)s * H2_ + h];
        float4v q4 = *(const float4v*)&Qb[(size_t)s * H2_ + h];
        pv = p4 * wv;
        qv = q4 * wv;
      }
      half4v phv = __builtin_convertvector(pv, half4v);
      half4v qhv = __builtin_convertvector(qv, half4v);
      *(half4v*)&S.ph[s][4 * c4] = phv;
      *(half4v*)&S.qh[s][4 * c4] = qhv;
      // norms from the SAME fp16 values (consistent with MFMA numerator)
      float4v pf = __builtin_convertvector(phv, float4v);
      float4v qf = __builtin_convertvector(qhv, float4v);
      np2a[jj] += pf.x * pf.x + pf.y * pf.y + pf.z * pf.z + pf.w * pf.w;
      nq2a[jj] += qf.x * qf.x + qf.y * qf.y + qf.z * qf.z + qf.w * qf.w;
    }
    __syncthreads();
#pragma unroll
    for (int ks = 0; ks < 2; ++ks) {
      half8v ah = *(const half8v*)&S.ph[16 * w + col][ks * 32 + quad * 8];
#pragma unroll
      for (int qt = 0; qt < 4; ++qt) {
        half8v bh = *(const half8v*)&S.qh[16 * qt + col][ks * 32 + quad * 8];
        acc[qt] = __builtin_amdgcn_mfma_f32_16x16x32_f16(ah, bh, acc[qt], 0, 0, 0);
      }
    }
  }
#pragma unroll
  for (int jj = 0; jj < 4; ++jj) {
    float a = np2a[jj], bb = nq2a[jj];
#pragma unroll
    for (int m = 1; m < 16; m <<= 1) {
      a += __shfl_xor(a, m);
      bb += __shfl_xor(bb, m);
    }
    if ((t & 15) == 0) {
      int s = (t >> 4) + 16 * jj;
      S.pn2[s] = a;
      S.qn2[s] = bb;
    }
  }
  __syncthreads();
  // C/D: row = quad*4+r (p_local), col = lane&15 (q_local) [m89/m91 verified]
  float pnv[4];
#pragma unroll
  for (int r = 0; r < 4; ++r) pnv[r] = sqrtf(S.pn2[16 * w + quad * 4 + r]);
  float rowm[4] = {NEG_INF, NEG_INF, NEG_INF, NEG_INF};
#pragma unroll
  for (int qt = 0; qt < 4; ++qt) {
    float qnv = sqrtf(S.qn2[16 * qt + col]);
    float cmv = NEG_INF;
#pragma unroll
    for (int r = 0; r < 4; ++r) {
      float c = acc[qt][r] / (pnv[r] * qnv);    // no EPS in reference maxpool
      rowm[r] = fmaxf(rowm[r], c);
      cmv = fmaxf(cmv, c);
    }
    cmv = fmaxf(cmv, __shfl_xor(cmv, 16));
    cmv = fmaxf(cmv, __shfl_xor(cmv, 32));
    if (quad == 0) S.colp[w][16 * qt + col] = cmv;
  }
#pragma unroll
  for (int m = 1; m < 16; m <<= 1)
#pragma unroll
    for (int r = 0; r < 4; ++r) rowm[r] = fmaxf(rowm[r], __shfl_xor(rowm[r], m));
  if (col == 0) {
#pragma unroll
    for (int r = 0; r < 4; ++r) {
      int p = 16 * w + quad * 4 + r;
      out[((size_t)b * S_ + p) * ROW_ + (2 + dir) * L_ + l] = rowm[r];
    }
  }
  __syncthreads();
  if (t < S_) {
    float m0 = fmaxf(fmaxf(S.colp[0][t], S.colp[1][t]), fmaxf(S.colp[2][t], S.colp[3][t]));
    out[OUTQ_OFF + ((size_t)b * S_ + t) * ROW_ + (2 + dir) * L_ + l] = m0;
  }
}

// ---------------- K1: maxpool first (heavy, starts early), then w^2, then cos.
__global__ __launch_bounds__(256) void k1(const float* __restrict__ P,
                                          const float* __restrict__ Q,
                                          const float* __restrict__ Wf,
                                          float* __restrict__ w2r,
                                          float* __restrict__ cosM,
                                          float* __restrict__ sumpart,
                                          float* __restrict__ sum_q,
                                          float* __restrict__ out) {
  extern __shared__ char smem[];
  int bid = blockIdx.x;
  if (bid < NB_MP) {
    maxpool_body(smem, bid, P, Q, Wf, out);
  } else if (bid < NB_MP + NB_W) {
    int i = (bid - NB_MP) * 256 + threadIdx.x;
    if (i < 8 * L_ * H_) {
      float v = Wf[i];
      w2r[i] = v * v;
    }
  } else {
    cos_body(smem, bid - (NB_MP + NB_W), P, Q, cosM, sumpart, sum_q);
  }
}

// ---------------- K2: r12-verified 512-thread structure; middle loop packed
// to float2 (v_pk_fma/v_pk_max halve VALU issue; per-k accumulation order
// unchanged -> identical mean sums), tail packed to float4 partials.
#define SG 4
struct OutsS {                      // 31264 B
  float u[600];
  float xP[SG][H_], xQ[SG][H_];
  float vmq[SG][H_], vmp[SG][H_], vxq[SG][H_], vxp[SG][H_];
  float sps[SG], sqs[SG];
};

__global__ __launch_bounds__(512) void k2(const float* __restrict__ P,
                                          const float* __restrict__ Q,
                                          const float* __restrict__ w2r,
                                          const float* __restrict__ cosM,
                                          const float* __restrict__ sumpart,
                                          const float* __restrict__ sum_q,
                                          float* __restrict__ out) {
  extern __shared__ char smem[];
  OutsS& S = *(OutsS*)smem;
  int bid = blockIdx.x;
  // XCD swizzle: bd = (bid&7) + 8*((bid>>3)&7); sg = bid>>6
  int x = bid & 7, j = bid >> 3;
  int bd = x + 8 * (j & 7);
  int sg = j >> 3;
  int s0 = sg * SG;
  int b = bd >> 1, dir = bd & 1;
  int t = threadIdx.x;
  // cos staged TRANSPOSED + interleaved: cosT[k][si] = cosC, cosT[k][4+si] = cosR
  float (*cosT)[8] = (float (*)[8])&S.u[0];     // 512 floats in u[600]
  const float* cm = cosM + (size_t)bd * S_ * S_;
  {
    int k = t >> 3, jj = t & 7, si = jj & 3;    // 512 entries, one per thread
    cosT[k][jj] = (jj < 4) ? cm[(size_t)k * S_ + s0 + si]
                           : cm[(size_t)(s0 + si) * S_ + k];
  }
  if (t < SG) {
    float a = 0.f;
    for (int pg = 0; pg < 16; ++pg) a += sumpart[((size_t)bd * 16 + pg) * S_ + s0 + t];
    S.sps[t] = a;
    S.sqs[t] = sum_q[bd * S_ + s0 + t];
  }
  int tgt = dir ? 0 : S_ - 1;
  const float* Pb = P + (size_t)b * S_ * H2_ + dir * H_;
  const float* Qb = Q + (size_t)b * S_ * H2_ + dir * H_;
  if (t < SG * 75) {                            // 300 b128 pairs, single round
    int si = t / 75, c4 = t - si * 75;
    *(float4v*)&S.xP[si][4 * c4] = *(const float4v*)&Pb[(size_t)(s0 + si) * H2_ + 4 * c4];
    *(float4v*)&S.xQ[si][4 * c4] = *(const float4v*)&Qb[(size_t)(s0 + si) * H2_ + 4 * c4];
  }
  __syncthreads();
  if (t < H_) {                                 // middle: single round, h = t
    int h = t;
    float2v amp01 = {0.f, 0.f}, amp23 = {0.f, 0.f};
    float2v amq01 = {0.f, 0.f}, amq23 = {0.f, 0.f};
    float2v axp01 = {NEG_INF, NEG_INF}, axp23 = {NEG_INF, NEG_INF};
    float2v axq01 = {NEG_INF, NEG_INF}, axq23 = {NEG_INF, NEG_INF};
#pragma unroll 4
    for (int k = 0; k < S_; ++k) {
      float pv = Pb[(size_t)k * H2_ + h];
      float qv = Qb[(size_t)k * H2_ + h];
      float4v cc = *(const float4v*)&cosT[k][0];
      float4v cr = *(const float4v*)&cosT[k][4];
      float2v cc01 = {cc.x, cc.y}, cc23 = {cc.z, cc.w};
      float2v cr01 = {cr.x, cr.y}, cr23 = {cr.z, cr.w};
      float2v m0 = pv * cc01;
      amp01 += m0; axp01 = __builtin_elementwise_max(axp01, m0);
      float2v m1 = pv * cc23;
      amp23 += m1; axp23 = __builtin_elementwise_max(axp23, m1);
      float2v m2 = qv * cr01;
      amq01 += m2; axq01 = __builtin_elementwise_max(axq01, m2);
      float2v m3 = qv * cr23;
      amq23 += m3; axq23 = __builtin_elementwise_max(axq23, m3);
    }
    S.vmq[0][h] = amq01.x / S.sqs[0];
    S.vmq[1][h] = amq01.y / S.sqs[1];
    S.vmq[2][h] = amq23.x / S.sqs[2];
    S.vmq[3][h] = amq23.y / S.sqs[3];
    S.vmp[0][h] = amp01.x / S.sps[0];
    S.vmp[1][h] = amp01.y / S.sps[1];
    S.vmp[2][h] = amp23.x / S.sps[2];
    S.vmp[3][h] = amp23.y / S.sps[3];
    S.vxq[0][h] = axq01.x; S.vxq[1][h] = axq01.y;
    S.vxq[2][h] = axq23.x; S.vxq[3][h] = axq23.y;
    S.vxp[0][h] = axp01.x; S.vxp[1][h] = axp01.y;
    S.vxp[2][h] = axp23.x; S.vxp[3][h] = axp23.y;
  }
  __syncthreads();
  float* tq = &S.u[0];
  float* tp = &S.u[300];
  if (t < 75) {
    *(float4v*)&tq[4 * t] = *(const float4v*)&Qb[(size_t)tgt * H2_ + 4 * t];
    *(float4v*)&tp[4 * t] = *(const float4v*)&Pb[(size_t)tgt * H2_ + 4 * t];
  }
  __syncthreads();
  // 480 jobs, single round; lanes share l -> w2r reads are broadcast lines.
  const int wb_[6] = {0, 0, 4, 4, 6, 6};
  if (t < 480) {
    int job = t;
    int l = job / 24;
    int g = job - l * 24;
    int pr = g >> 2, si = g & 3;
    const float* xv = (pr & 1) ? S.xQ[si] : S.xP[si];
    const float* y;
    if (pr == 0) y = tq;
    else if (pr == 1) y = tp;
    else if (pr == 2) y = S.vmq[si];
    else if (pr == 3) y = S.vmp[si];
    else if (pr == 4) y = S.vxq[si];
    else y = S.vxp[si];
    int widx = wb_[pr] + dir;
    const float* wp = w2r + (size_t)widx * (L_ * H_) + (size_t)l * H_;   // row layout
    float4v a1v = {0.f, 0.f, 0.f, 0.f};
    float4v a2v = {0.f, 0.f, 0.f, 0.f};
    float4v a3v = {0.f, 0.f, 0.f, 0.f};
    for (int h4 = 0; h4 < H_; h4 += 4) {
      float4v wv = *(const float4v*)&wp[h4];
      float4v xx = *(const float4v*)&xv[h4];
      float4v yy = *(const float4v*)&y[h4];
      float4v wx = wv * xx;
      float4v wy = wv * yy;
      a1v = wx * yy + a1v;
      a2v = wx * xx + a2v;
      a3v = wy * yy + a3v;
    }
    float a1 = (a1v.x + a1v.y) + (a1v.z + a1v.w);
    float a2 = (a2v.x + a2v.y) + (a2v.z + a2v.w);
    float a3 = (a3v.x + a3v.y) + (a3v.z + a3v.w);
    float den = fmaxf(sqrtf(a2) * sqrtf(a3), 1e-8f);   // EPS per _mp_cos
    float c = a1 / den;
    int s = s0 + si;
    size_t base = ((pr & 1) ? OUTQ_OFF : 0) + ((size_t)b * S_ + s) * ROW_;
    out[base + (size_t)widx * L_ + l] = c;
  }
}

extern "C" void kernel_launch(void* const* d_in, const int* in_sizes, int n_in,
                              void* d_out, int out_size, void* d_ws, size_t ws_size,
                              hipStream_t stream) {
  (void)out_size; (void)ws_size;
  int iw = 2;
  for (int i = 0; i < n_in; ++i) if (in_sizes[i] == 8 * L_ * H_) iw = i;
  int io[2] = {0, 1}, k = 0;
  for (int i = 0; i < n_in && k < 2; ++i) if (i != iw) io[k++] = i;
  const float* P  = (const float*)d_in[io[0]];
  const float* Q  = (const float*)d_in[io[1]];
  const float* Wf = (const float*)d_in[iw];
  float* out = (float*)d_out;

  float* ws = (float*)d_ws;             // ~1.52 MB
  float* w2r     = ws;                  // 48000
  float* cosM    = w2r + 48000;         // 262144
  float* sumpart = cosM + 262144;       // 65536 (64 bd * 16 pg * 64 q)
  float* sum_q   = sumpart + 65536;     // 4096

  size_t sh1 = sizeof(CosS) > sizeof(MaxpoolS) ? sizeof(CosS) : sizeof(MaxpoolS);
  k1<<<NB_MP + NB_W + NB_COS, 256, sh1, stream>>>(P, Q, Wf, w2r, cosM, sumpart, sum_q, out);
  k2<<<B_ * 2 * 16, 512, sizeof(OutsS), stream>>>(P, Q, w2r, cosM, sumpart, sum_q, out);
}

// Round 14
// 138.007 us; speedup vs baseline: 1.7158x; 1.7158x over previous
//
#include <hip/hip_runtime.h>

#define B_ 32
#define S_ 64
#define H_ 300
#define H2_ 600
#define L_ 20
#define ROW_ 160                    // 8 pieces * 20
#define OUTQ_OFF ((size_t)B_ * S_ * ROW_)
#define NEG_INF -3.402823466e38f

#define NB_MP 1280                  // 64 bd * 20 l   (dispatched first)
#define NB_W 188                    // 48000 / 256 rounded up
#define NB_COS 1024                 // 64 bd * 16 pg (4 p-rows each)

typedef __attribute__((ext_vector_type(8))) _Float16 half8v;   // 8 f16 = 4 VGPRs
typedef __attribute__((ext_vector_type(4))) _Float16 half4v;   // 4 f16 = 8 B
typedef __attribute__((ext_vector_type(4))) float float4v;
typedef __attribute__((ext_vector_type(2))) float float2v;

// ---------------- cos block: (bd, pg) -> 4 p-rows x 64 q, norms in-block.
// EXACT r12-verified SCALAR body (r13's float4 accumulators spilled: VGPR 256,
// 141MB scratch writes, 170us. Scalar fmaf chains keep VGPR ~64).
struct CosS {                       // 19008 B
  float xq[S_][65];                 // stride 65: 2-way scalar reads (free)
  float xp[4][68];                  // 272 B rows, 16-B aligned, broadcast b128
  float qn_l[S_];
  float cp[4][S_];
};

__device__ __forceinline__ void cos_body(char* smem, int bid,
                                         const float* __restrict__ P,
                                         const float* __restrict__ Q,
                                         float* __restrict__ cosM,
                                         float* __restrict__ sumpart,
                                         float* __restrict__ sum_q) {
  CosS& S = *(CosS*)smem;
  // XCD swizzle: bd = (bid&7) + 8*((bid>>3)&7); pg = bid>>6  (bijective 8x8x16)
  int x = bid & 7, j = bid >> 3;
  int bd = x + 8 * (j & 7);
  int pg = bid >> 6;
  int b = bd >> 1, dir = bd & 1;
  int t = threadIdx.x;
  int q = t & 63, pr = t >> 6;
  const float* Pb = P + (size_t)b * S_ * H2_ + dir * H_;
  const float* Qb = Q + (size_t)b * S_ * H2_ + dir * H_;
  float dot = 0.f, np2 = 0.f, nq2 = 0.f;
  for (int c0 = 0; c0 < H_; c0 += 64) {          // 5 chunks (last zero-padded)
    __syncthreads();
#pragma unroll
    for (int jj = 0; jj < 4; ++jj) {             // 64 rows x 16 groups static
      int idx = t + 256 * jj;
      int s = idx >> 4, g = idx & 15;
      int h = c0 + 4 * g;
      float4v v = {0.f, 0.f, 0.f, 0.f};
      if (h < 297) v = *(const float4v*)&Qb[(size_t)s * H2_ + h];
      S.xq[s][4 * g + 0] = v.x; S.xq[s][4 * g + 1] = v.y;
      S.xq[s][4 * g + 2] = v.z; S.xq[s][4 * g + 3] = v.w;
    }
    if (t < 64) {                                // 4 rows x 16 groups static
      int s = t >> 4, g = t & 15;
      int h = c0 + 4 * g;
      float4v v = {0.f, 0.f, 0.f, 0.f};
      if (h < 297) v = *(const float4v*)&Pb[(size_t)(pg * 4 + s) * H2_ + h];
      *(float4v*)&S.xp[s][4 * g] = v;
    }
    __syncthreads();
    for (int hh = 0; hh < 64; hh += 4) {
      float4v av = *(const float4v*)&S.xp[pr][hh];       // wave-broadcast (free)
      float q0 = S.xq[q][hh + 0];
      float q1 = S.xq[q][hh + 1];
      float q2 = S.xq[q][hh + 2];
      float q3 = S.xq[q][hh + 3];
      dot = fmaf(av.x, q0, dot); dot = fmaf(av.y, q1, dot);
      dot = fmaf(av.z, q2, dot); dot = fmaf(av.w, q3, dot);
      np2 = fmaf(av.x, av.x, np2); np2 = fmaf(av.y, av.y, np2);
      np2 = fmaf(av.z, av.z, np2); np2 = fmaf(av.w, av.w, np2);
      if (pr == 0) {                                     // wave-uniform branch
        nq2 = fmaf(q0, q0, nq2); nq2 = fmaf(q1, q1, nq2);
        nq2 = fmaf(q2, q2, nq2); nq2 = fmaf(q3, q3, nq2);
      }
    }
  }
  if (pr == 0) S.qn_l[q] = sqrtf(nq2);
  __syncthreads();
  float pn = sqrtf(np2);                                 // uniform per wave
  float c = dot / (pn * S.qn_l[q]);
  int p = pg * 4 + pr;
  cosM[(size_t)bd * S_ * S_ + (size_t)p * S_ + q] = c;
  float rs = c;
#pragma unroll
  for (int m = 1; m < 64; m <<= 1) rs += __shfl_xor(rs, m);
  if (q == 0) sum_q[bd * S_ + p] = rs;
  S.cp[pr][q] = c;
  __syncthreads();
  if (t < S_)
    sumpart[((size_t)bd * 16 + pg) * S_ + t] =
        S.cp[0][t] + S.cp[1][t] + S.cp[2][t] + S.cp[3][t];
}

// ---------------- maxpool block (byte-identical to r12-verified version)
#define HP 72                       // padded fp16 row: 144 B, 16-B aligned f16x8 groups
struct MaxpoolS {                   // 21168 B
  _Float16 ph[S_][HP];
  _Float16 qh[S_][HP];
  float w1s[H_];
  float pn2[S_], qn2[S_];
  float colp[4][S_];
};

__device__ __forceinline__ void maxpool_body(char* smem, int bid,
                                             const float* __restrict__ P,
                                             const float* __restrict__ Q,
                                             const float* __restrict__ Wf,
                                             float* __restrict__ out) {
  MaxpoolS& S = *(MaxpoolS*)smem;
  // XCD swizzle: bd = (bid&7) + 8*((bid>>3)&7); l = bid>>6
  int x = bid & 7, j = bid >> 3;
  int bd = x + 8 * (j & 7);
  int l = j >> 3;
  int b = bd >> 1, dir = bd & 1;
  int t = threadIdx.x;
  int w = t >> 6, lane = t & 63, quad = lane >> 4, col = lane & 15;
  const float* wg = Wf + (size_t)(2 + dir) * L_ * H_ + (size_t)l * H_;
  if (t < 75) {
    float4v v = *(const float4v*)&wg[4 * t];
    float4v a = {fabsf(v.x), fabsf(v.y), fabsf(v.z), fabsf(v.w)};
    *(float4v*)&S.w1s[4 * t] = a;
  }
  const float* Pb = P + (size_t)b * S_ * H2_ + dir * H_;
  const float* Qb = Q + (size_t)b * S_ * H2_ + dir * H_;
  float4v acc[4];
#pragma unroll
  for (int qt = 0; qt < 4; ++qt) acc[qt] = (float4v){0.f, 0.f, 0.f, 0.f};
  float np2a[4] = {0.f, 0.f, 0.f, 0.f};
  float nq2a[4] = {0.f, 0.f, 0.f, 0.f};
  for (int h0 = 0; h0 < H_; h0 += 64) {          // 5 chunks (last zero-padded)
    __syncthreads();
#pragma unroll
    for (int jj = 0; jj < 4; ++jj) {             // float4 staging: 4 iters/chunk
      int idx = t + 256 * jj;
      int s = idx >> 4, c4 = idx & 15;
      int h = h0 + 4 * c4;
      float4v pv = {0.f, 0.f, 0.f, 0.f}, qv = {0.f, 0.f, 0.f, 0.f};
      if (h < 297) {                             // full group valid (h+3 <= 299)
        float4v wv = *(const float4v*)&S.w1s[h];
        float4v p4 = *(const float4v*)&Pb[(size_t)s * H2_ + h];
        float4v q4 = *(const float4v*)&Qb[(size_t)s * H2_ + h];
        pv = p4 * wv;
        qv = q4 * wv;
      }
      half4v phv = __builtin_convertvector(pv, half4v);
      half4v qhv = __builtin_convertvector(qv, half4v);
      *(half4v*)&S.ph[s][4 * c4] = phv;
      *(half4v*)&S.qh[s][4 * c4] = qhv;
      // norms from the SAME fp16 values (consistent with MFMA numerator)
      float4v pf = __builtin_convertvector(phv, float4v);
      float4v qf = __builtin_convertvector(qhv, float4v);
      np2a[jj] += pf.x * pf.x + pf.y * pf.y + pf.z * pf.z + pf.w * pf.w;
      nq2a[jj] += qf.x * qf.x + qf.y * qf.y + qf.z * qf.z + qf.w * qf.w;
    }
    __syncthreads();
#pragma unroll
    for (int ks = 0; ks < 2; ++ks) {
      half8v ah = *(const half8v*)&S.ph[16 * w + col][ks * 32 + quad * 8];
#pragma unroll
      for (int qt = 0; qt < 4; ++qt) {
        half8v bh = *(const half8v*)&S.qh[16 * qt + col][ks * 32 + quad * 8];
        acc[qt] = __builtin_amdgcn_mfma_f32_16x16x32_f16(ah, bh, acc[qt], 0, 0, 0);
      }
    }
  }
#pragma unroll
  for (int jj = 0; jj < 4; ++jj) {
    float a = np2a[jj], bb = nq2a[jj];
#pragma unroll
    for (int m = 1; m < 16; m <<= 1) {
      a += __shfl_xor(a, m);
      bb += __shfl_xor(bb, m);
    }
    if ((t & 15) == 0) {
      int s = (t >> 4) + 16 * jj;
      S.pn2[s] = a;
      S.qn2[s] = bb;
    }
  }
  __syncthreads();
  // C/D: row = quad*4+r (p_local), col = lane&15 (q_local) [m89/m91 verified]
  float pnv[4];
#pragma unroll
  for (int r = 0; r < 4; ++r) pnv[r] = sqrtf(S.pn2[16 * w + quad * 4 + r]);
  float rowm[4] = {NEG_INF, NEG_INF, NEG_INF, NEG_INF};
#pragma unroll
  for (int qt = 0; qt < 4; ++qt) {
    float qnv = sqrtf(S.qn2[16 * qt + col]);
    float cmv = NEG_INF;
#pragma unroll
    for (int r = 0; r < 4; ++r) {
      float c = acc[qt][r] / (pnv[r] * qnv);    // no EPS in reference maxpool
      rowm[r] = fmaxf(rowm[r], c);
      cmv = fmaxf(cmv, c);
    }
    cmv = fmaxf(cmv, __shfl_xor(cmv, 16));
    cmv = fmaxf(cmv, __shfl_xor(cmv, 32));
    if (quad == 0) S.colp[w][16 * qt + col] = cmv;
  }
#pragma unroll
  for (int m = 1; m < 16; m <<= 1)
#pragma unroll
    for (int r = 0; r < 4; ++r) rowm[r] = fmaxf(rowm[r], __shfl_xor(rowm[r], m));
  if (col == 0) {
#pragma unroll
    for (int r = 0; r < 4; ++r) {
      int p = 16 * w + quad * 4 + r;
      out[((size_t)b * S_ + p) * ROW_ + (2 + dir) * L_ + l] = rowm[r];
    }
  }
  __syncthreads();
  if (t < S_) {
    float m0 = fmaxf(fmaxf(S.colp[0][t], S.colp[1][t]), fmaxf(S.colp[2][t], S.colp[3][t]));
    out[OUTQ_OFF + ((size_t)b * S_ + t) * ROW_ + (2 + dir) * L_ + l] = m0;
  }
}

// ---------------- K1: maxpool first (heavy, starts early), then w^2, then cos.
__global__ __launch_bounds__(256) void k1(const float* __restrict__ P,
                                          const float* __restrict__ Q,
                                          const float* __restrict__ Wf,
                                          float* __restrict__ w2r,
                                          float* __restrict__ cosM,
                                          float* __restrict__ sumpart,
                                          float* __restrict__ sum_q,
                                          float* __restrict__ out) {
  extern __shared__ char smem[];
  int bid = blockIdx.x;
  if (bid < NB_MP) {
    maxpool_body(smem, bid, P, Q, Wf, out);
  } else if (bid < NB_MP + NB_W) {
    int i = (bid - NB_MP) * 256 + threadIdx.x;
    if (i < 8 * L_ * H_) {
      float v = Wf[i];
      w2r[i] = v * v;
    }
  } else {
    cos_body(smem, bid - (NB_MP + NB_W), P, Q, cosM, sumpart, sum_q);
  }
}

// ---------------- K2: r13-verified packed version (middle loop float2
// v_pk_fma/v_pk_max; tail float4 partials). ~27-30us in r13.
#define SG 4
struct OutsS {                      // 31264 B
  float u[600];
  float xP[SG][H_], xQ[SG][H_];
  float vmq[SG][H_], vmp[SG][H_], vxq[SG][H_], vxp[SG][H_];
  float sps[SG], sqs[SG];
};

__global__ __launch_bounds__(512) void k2(const float* __restrict__ P,
                                          const float* __restrict__ Q,
                                          const float* __restrict__ w2r,
                                          const float* __restrict__ cosM,
                                          const float* __restrict__ sumpart,
                                          const float* __restrict__ sum_q,
                                          float* __restrict__ out) {
  extern __shared__ char smem[];
  OutsS& S = *(OutsS*)smem;
  int bid = blockIdx.x;
  // XCD swizzle: bd = (bid&7) + 8*((bid>>3)&7); sg = bid>>6
  int x = bid & 7, j = bid >> 3;
  int bd = x + 8 * (j & 7);
  int sg = j >> 3;
  int s0 = sg * SG;
  int b = bd >> 1, dir = bd & 1;
  int t = threadIdx.x;
  // cos staged TRANSPOSED + interleaved: cosT[k][si] = cosC, cosT[k][4+si] = cosR
  float (*cosT)[8] = (float (*)[8])&S.u[0];     // 512 floats in u[600]
  const float* cm = cosM + (size_t)bd * S_ * S_;
  {
    int k = t >> 3, jj = t & 7, si = jj & 3;    // 512 entries, one per thread
    cosT[k][jj] = (jj < 4) ? cm[(size_t)k * S_ + s0 + si]
                           : cm[(size_t)(s0 + si) * S_ + k];
  }
  if (t < SG) {
    float a = 0.f;
    for (int pg = 0; pg < 16; ++pg) a += sumpart[((size_t)bd * 16 + pg) * S_ + s0 + t];
    S.sps[t] = a;
    S.sqs[t] = sum_q[bd * S_ + s0 + t];
  }
  int tgt = dir ? 0 : S_ - 1;
  const float* Pb = P + (size_t)b * S_ * H2_ + dir * H_;
  const float* Qb = Q + (size_t)b * S_ * H2_ + dir * H_;
  if (t < SG * 75) {                            // 300 b128 pairs, single round
    int si = t / 75, c4 = t - si * 75;
    *(float4v*)&S.xP[si][4 * c4] = *(const float4v*)&Pb[(size_t)(s0 + si) * H2_ + 4 * c4];
    *(float4v*)&S.xQ[si][4 * c4] = *(const float4v*)&Qb[(size_t)(s0 + si) * H2_ + 4 * c4];
  }
  __syncthreads();
  if (t < H_) {                                 // middle: single round, h = t
    int h = t;
    float2v amp01 = {0.f, 0.f}, amp23 = {0.f, 0.f};
    float2v amq01 = {0.f, 0.f}, amq23 = {0.f, 0.f};
    float2v axp01 = {NEG_INF, NEG_INF}, axp23 = {NEG_INF, NEG_INF};
    float2v axq01 = {NEG_INF, NEG_INF}, axq23 = {NEG_INF, NEG_INF};
#pragma unroll 4
    for (int k = 0; k < S_; ++k) {
      float pv = Pb[(size_t)k * H2_ + h];
      float qv = Qb[(size_t)k * H2_ + h];
      float4v cc = *(const float4v*)&cosT[k][0];
      float4v cr = *(const float4v*)&cosT[k][4];
      float2v cc01 = {cc.x, cc.y}, cc23 = {cc.z, cc.w};
      float2v cr01 = {cr.x, cr.y}, cr23 = {cr.z, cr.w};
      float2v m0 = pv * cc01;
      amp01 += m0; axp01 = __builtin_elementwise_max(axp01, m0);
      float2v m1 = pv * cc23;
      amp23 += m1; axp23 = __builtin_elementwise_max(axp23, m1);
      float2v m2 = qv * cr01;
      amq01 += m2; axq01 = __builtin_elementwise_max(axq01, m2);
      float2v m3 = qv * cr23;
      amq23 += m3; axq23 = __builtin_elementwise_max(axq23, m3);
    }
    S.vmq[0][h] = amq01.x / S.sqs[0];
    S.vmq[1][h] = amq01.y / S.sqs[1];
    S.vmq[2][h] = amq23.x / S.sqs[2];
    S.vmq[3][h] = amq23.y / S.sqs[3];
    S.vmp[0][h] = amp01.x / S.sps[0];
    S.vmp[1][h] = amp01.y / S.sps[1];
    S.vmp[2][h] = amp23.x / S.sps[2];
    S.vmp[3][h] = amp23.y / S.sps[3];
    S.vxq[0][h] = axq01.x; S.vxq[1][h] = axq01.y;
    S.vxq[2][h] = axq23.x; S.vxq[3][h] = axq23.y;
    S.vxp[0][h] = axp01.x; S.vxp[1][h] = axp01.y;
    S.vxp[2][h] = axp23.x; S.vxp[3][h] = axp23.y;
  }
  __syncthreads();
  float* tq = &S.u[0];
  float* tp = &S.u[300];
  if (t < 75) {
    *(float4v*)&tq[4 * t] = *(const float4v*)&Qb[(size_t)tgt * H2_ + 4 * t];
    *(float4v*)&tp[4 * t] = *(const float4v*)&Pb[(size_t)tgt * H2_ + 4 * t];
  }
  __syncthreads();
  // 480 jobs, single round; lanes share l -> w2r reads are broadcast lines.
  const int wb_[6] = {0, 0, 4, 4, 6, 6};
  if (t < 480) {
    int job = t;
    int l = job / 24;
    int g = job - l * 24;
    int pr = g >> 2, si = g & 3;
    const float* xv = (pr & 1) ? S.xQ[si] : S.xP[si];
    const float* y;
    if (pr == 0) y = tq;
    else if (pr == 1) y = tp;
    else if (pr == 2) y = S.vmq[si];
    else if (pr == 3) y = S.vmp[si];
    else if (pr == 4) y = S.vxq[si];
    else y = S.vxp[si];
    int widx = wb_[pr] + dir;
    const float* wp = w2r + (size_t)widx * (L_ * H_) + (size_t)l * H_;   // row layout
    float4v a1v = {0.f, 0.f, 0.f, 0.f};
    float4v a2v = {0.f, 0.f, 0.f, 0.f};
    float4v a3v = {0.f, 0.f, 0.f, 0.f};
    for (int h4 = 0; h4 < H_; h4 += 4) {
      float4v wv = *(const float4v*)&wp[h4];
      float4v xx = *(const float4v*)&xv[h4];
      float4v yy = *(const float4v*)&y[h4];
      float4v wx = wv * xx;
      float4v wy = wv * yy;
      a1v = wx * yy + a1v;
      a2v = wx * xx + a2v;
      a3v = wy * yy + a3v;
    }
    float a1 = (a1v.x + a1v.y) + (a1v.z + a1v.w);
    float a2 = (a2v.x + a2v.y) + (a2v.z + a2v.w);
    float a3 = (a3v.x + a3v.y) + (a3v.z + a3v.w);
    float den = fmaxf(sqrtf(a2) * sqrtf(a3), 1e-8f);   // EPS per _mp_cos
    float c = a1 / den;
    int s = s0 + si;
    size_t base = ((pr & 1) ? OUTQ_OFF : 0) + ((size_t)b * S_ + s) * ROW_;
    out[base + (size_t)widx * L_ + l] = c;
  }
}

extern "C" void kernel_launch(void* const* d_in, const int* in_sizes, int n_in,
                              void* d_out, int out_size, void* d_ws, size_t ws_size,
                              hipStream_t stream) {
  (void)out_size; (void)ws_size;
  int iw = 2;
  for (int i = 0; i < n_in; ++i) if (in_sizes[i] == 8 * L_ * H_) iw = i;
  int io[2] = {0, 1}, k = 0;
  for (int i = 0; i < n_in && k < 2; ++i) if (i != iw) io[k++] = i;
  const float* P  = (const float*)d_in[io[0]];
  const float* Q  = (const float*)d_in[io[1]];
  const float* Wf = (const float*)d_in[iw];
  float* out = (float*)d_out;

  float* ws = (float*)d_ws;             // ~1.52 MB
  float* w2r     = ws;                  // 48000
  float* cosM    = w2r + 48000;         // 262144
  float* sumpart = cosM + 262144;       // 65536 (64 bd * 16 pg * 64 q)
  float* sum_q   = sumpart + 65536;     // 4096

  size_t sh1 = sizeof(CosS) > sizeof(MaxpoolS) ? sizeof(CosS) : sizeof(MaxpoolS);
  k1<<<NB_MP + NB_W + NB_COS, 256, sh1, stream>>>(P, Q, Wf, w2r, cosM, sumpart, sum_q, out);
  k2<<<B_ * 2 * 16, 512, sizeof(OutsS), stream>>>(P, Q, w2r, cosM, sumpart, sum_q, out);
}

// Round 15
// 137.126 us; speedup vs baseline: 1.7268x; 1.0064x over previous
//
#include <hip/hip_runtime.h>

#define B_ 32
#define S_ 64
#define H_ 300
#define H2_ 600
#define L_ 20
#define ROW_ 160                    // 8 pieces * 20
#define OUTQ_OFF ((size_t)B_ * S_ * ROW_)
#define NEG_INF -3.402823466e38f

#define NB_MP 1280                  // 64 bd * 20 l   (dispatched first)
#define NB_W 188                    // 48000 / 256 rounded up
#define NB_COS 1024                 // 64 bd * 16 pg (4 p-rows each)

typedef __attribute__((ext_vector_type(8))) _Float16 half8v;   // 8 f16 = 4 VGPRs
typedef __attribute__((ext_vector_type(4))) _Float16 half4v;   // 4 f16 = 8 B
typedef __attribute__((ext_vector_type(4))) float float4v;
typedef __attribute__((ext_vector_type(2))) float float2v;

// ---------------- cos block: (bd, pg) -> 4 p-rows x 64 q, norms in-block.
// EXACT r14-verified SCALAR body.
struct CosS {                       // 19008 B
  float xq[S_][65];                 // stride 65: 2-way scalar reads (free)
  float xp[4][68];                  // 272 B rows, 16-B aligned, broadcast b128
  float qn_l[S_];
  float cp[4][S_];
};

__device__ __forceinline__ void cos_body(char* smem, int bid,
                                         const float* __restrict__ P,
                                         const float* __restrict__ Q,
                                         float* __restrict__ cosM,
                                         float* __restrict__ sumpart,
                                         float* __restrict__ sum_q) {
  CosS& S = *(CosS*)smem;
  // XCD swizzle: bd = (bid&7) + 8*((bid>>3)&7); pg = bid>>6  (bijective 8x8x16)
  int x = bid & 7, j = bid >> 3;
  int bd = x + 8 * (j & 7);
  int pg = bid >> 6;
  int b = bd >> 1, dir = bd & 1;
  int t = threadIdx.x;
  int q = t & 63, pr = t >> 6;
  const float* Pb = P + (size_t)b * S_ * H2_ + dir * H_;
  const float* Qb = Q + (size_t)b * S_ * H2_ + dir * H_;
  float dot = 0.f, np2 = 0.f, nq2 = 0.f;
  for (int c0 = 0; c0 < H_; c0 += 64) {          // 5 chunks (last zero-padded)
    __syncthreads();
#pragma unroll
    for (int jj = 0; jj < 4; ++jj) {             // 64 rows x 16 groups static
      int idx = t + 256 * jj;
      int s = idx >> 4, g = idx & 15;
      int h = c0 + 4 * g;
      float4v v = {0.f, 0.f, 0.f, 0.f};
      if (h < 297) v = *(const float4v*)&Qb[(size_t)s * H2_ + h];
      S.xq[s][4 * g + 0] = v.x; S.xq[s][4 * g + 1] = v.y;
      S.xq[s][4 * g + 2] = v.z; S.xq[s][4 * g + 3] = v.w;
    }
    if (t < 64) {                                // 4 rows x 16 groups static
      int s = t >> 4, g = t & 15;
      int h = c0 + 4 * g;
      float4v v = {0.f, 0.f, 0.f, 0.f};
      if (h < 297) v = *(const float4v*)&Pb[(size_t)(pg * 4 + s) * H2_ + h];
      *(float4v*)&S.xp[s][4 * g] = v;
    }
    __syncthreads();
    for (int hh = 0; hh < 64; hh += 4) {
      float4v av = *(const float4v*)&S.xp[pr][hh];       // wave-broadcast (free)
      float q0 = S.xq[q][hh + 0];
      float q1 = S.xq[q][hh + 1];
      float q2 = S.xq[q][hh + 2];
      float q3 = S.xq[q][hh + 3];
      dot = fmaf(av.x, q0, dot); dot = fmaf(av.y, q1, dot);
      dot = fmaf(av.z, q2, dot); dot = fmaf(av.w, q3, dot);
      np2 = fmaf(av.x, av.x, np2); np2 = fmaf(av.y, av.y, np2);
      np2 = fmaf(av.z, av.z, np2); np2 = fmaf(av.w, av.w, np2);
      if (pr == 0) {                                     // wave-uniform branch
        nq2 = fmaf(q0, q0, nq2); nq2 = fmaf(q1, q1, nq2);
        nq2 = fmaf(q2, q2, nq2); nq2 = fmaf(q3, q3, nq2);
      }
    }
  }
  if (pr == 0) S.qn_l[q] = sqrtf(nq2);
  __syncthreads();
  float pn = sqrtf(np2);                                 // uniform per wave
  float c = dot / (pn * S.qn_l[q]);
  int p = pg * 4 + pr;
  cosM[(size_t)bd * S_ * S_ + (size_t)p * S_ + q] = c;
  float rs = c;
#pragma unroll
  for (int m = 1; m < 64; m <<= 1) rs += __shfl_xor(rs, m);
  if (q == 0) sum_q[bd * S_ + p] = rs;
  S.cp[pr][q] = c;
  __syncthreads();
  if (t < S_)
    sumpart[((size_t)bd * 16 + pg) * S_ + t] =
        S.cp[0][t] + S.cp[1][t] + S.cp[2][t] + S.cp[3][t];
}

// ---------------- maxpool block (byte-identical to r14-verified version)
#define HP 72                       // padded fp16 row: 144 B, 16-B aligned f16x8 groups
struct MaxpoolS {                   // 21168 B
  _Float16 ph[S_][HP];
  _Float16 qh[S_][HP];
  float w1s[H_];
  float pn2[S_], qn2[S_];
  float colp[4][S_];
};

__device__ __forceinline__ void maxpool_body(char* smem, int bid,
                                             const float* __restrict__ P,
                                             const float* __restrict__ Q,
                                             const float* __restrict__ Wf,
                                             float* __restrict__ out) {
  MaxpoolS& S = *(MaxpoolS*)smem;
  // XCD swizzle: bd = (bid&7) + 8*((bid>>3)&7); l = bid>>6
  int x = bid & 7, j = bid >> 3;
  int bd = x + 8 * (j & 7);
  int l = j >> 3;
  int b = bd >> 1, dir = bd & 1;
  int t = threadIdx.x;
  int w = t >> 6, lane = t & 63, quad = lane >> 4, col = lane & 15;
  const float* wg = Wf + (size_t)(2 + dir) * L_ * H_ + (size_t)l * H_;
  if (t < 75) {
    float4v v = *(const float4v*)&wg[4 * t];
    float4v a = {fabsf(v.x), fabsf(v.y), fabsf(v.z), fabsf(v.w)};
    *(float4v*)&S.w1s[4 * t] = a;
  }
  const float* Pb = P + (size_t)b * S_ * H2_ + dir * H_;
  const float* Qb = Q + (size_t)b * S_ * H2_ + dir * H_;
  float4v acc[4];
#pragma unroll
  for (int qt = 0; qt < 4; ++qt) acc[qt] = (float4v){0.f, 0.f, 0.f, 0.f};
  float np2a[4] = {0.f, 0.f, 0.f, 0.f};
  float nq2a[4] = {0.f, 0.f, 0.f, 0.f};
  for (int h0 = 0; h0 < H_; h0 += 64) {          // 5 chunks (last zero-padded)
    __syncthreads();
#pragma unroll
    for (int jj = 0; jj < 4; ++jj) {             // float4 staging: 4 iters/chunk
      int idx = t + 256 * jj;
      int s = idx >> 4, c4 = idx & 15;
      int h = h0 + 4 * c4;
      float4v pv = {0.f, 0.f, 0.f, 0.f}, qv = {0.f, 0.f, 0.f, 0.f};
      if (h < 297) {                             // full group valid (h+3 <= 299)
        float4v wv = *(const float4v*)&S.w1s[h];
        float4v p4 = *(const float4v*)&Pb[(size_t)s * H2_ + h];
        float4v q4 = *(const float4v*)&Qb[(size_t)s * H2_ + h];
        pv = p4 * wv;
        qv = q4 * wv;
      }
      half4v phv = __builtin_convertvector(pv, half4v);
      half4v qhv = __builtin_convertvector(qv, half4v);
      *(half4v*)&S.ph[s][4 * c4] = phv;
      *(half4v*)&S.qh[s][4 * c4] = qhv;
      // norms from the SAME fp16 values (consistent with MFMA numerator)
      float4v pf = __builtin_convertvector(phv, float4v);
      float4v qf = __builtin_convertvector(qhv, float4v);
      np2a[jj] += pf.x * pf.x + pf.y * pf.y + pf.z * pf.z + pf.w * pf.w;
      nq2a[jj] += qf.x * qf.x + qf.y * qf.y + qf.z * qf.z + qf.w * qf.w;
    }
    __syncthreads();
#pragma unroll
    for (int ks = 0; ks < 2; ++ks) {
      half8v ah = *(const half8v*)&S.ph[16 * w + col][ks * 32 + quad * 8];
#pragma unroll
      for (int qt = 0; qt < 4; ++qt) {
        half8v bh = *(const half8v*)&S.qh[16 * qt + col][ks * 32 + quad * 8];
        acc[qt] = __builtin_amdgcn_mfma_f32_16x16x32_f16(ah, bh, acc[qt], 0, 0, 0);
      }
    }
  }
#pragma unroll
  for (int jj = 0; jj < 4; ++jj) {
    float a = np2a[jj], bb = nq2a[jj];
#pragma unroll
    for (int m = 1; m < 16; m <<= 1) {
      a += __shfl_xor(a, m);
      bb += __shfl_xor(bb, m);
    }
    if ((t & 15) == 0) {
      int s = (t >> 4) + 16 * jj;
      S.pn2[s] = a;
      S.qn2[s] = bb;
    }
  }
  __syncthreads();
  // C/D: row = quad*4+r (p_local), col = lane&15 (q_local) [m89/m91 verified]
  float pnv[4];
#pragma unroll
  for (int r = 0; r < 4; ++r) pnv[r] = sqrtf(S.pn2[16 * w + quad * 4 + r]);
  float rowm[4] = {NEG_INF, NEG_INF, NEG_INF, NEG_INF};
#pragma unroll
  for (int qt = 0; qt < 4; ++qt) {
    float qnv = sqrtf(S.qn2[16 * qt + col]);
    float cmv = NEG_INF;
#pragma unroll
    for (int r = 0; r < 4; ++r) {
      float c = acc[qt][r] / (pnv[r] * qnv);    // no EPS in reference maxpool
      rowm[r] = fmaxf(rowm[r], c);
      cmv = fmaxf(cmv, c);
    }
    cmv = fmaxf(cmv, __shfl_xor(cmv, 16));
    cmv = fmaxf(cmv, __shfl_xor(cmv, 32));
    if (quad == 0) S.colp[w][16 * qt + col] = cmv;
  }
#pragma unroll
  for (int m = 1; m < 16; m <<= 1)
#pragma unroll
    for (int r = 0; r < 4; ++r) rowm[r] = fmaxf(rowm[r], __shfl_xor(rowm[r], m));
  if (col == 0) {
#pragma unroll
    for (int r = 0; r < 4; ++r) {
      int p = 16 * w + quad * 4 + r;
      out[((size_t)b * S_ + p) * ROW_ + (2 + dir) * L_ + l] = rowm[r];
    }
  }
  __syncthreads();
  if (t < S_) {
    float m0 = fmaxf(fmaxf(S.colp[0][t], S.colp[1][t]), fmaxf(S.colp[2][t], S.colp[3][t]));
    out[OUTQ_OFF + ((size_t)b * S_ + t) * ROW_ + (2 + dir) * L_ + l] = m0;
  }
}

// ---------------- K1: maxpool first (heavy, starts early), then w^2, then cos.
__global__ __launch_bounds__(256) void k1(const float* __restrict__ P,
                                          const float* __restrict__ Q,
                                          const float* __restrict__ Wf,
                                          float* __restrict__ w2r,
                                          float* __restrict__ cosM,
                                          float* __restrict__ sumpart,
                                          float* __restrict__ sum_q,
                                          float* __restrict__ out) {
  extern __shared__ char smem[];
  int bid = blockIdx.x;
  if (bid < NB_MP) {
    maxpool_body(smem, bid, P, Q, Wf, out);
  } else if (bid < NB_MP + NB_W) {
    int i = (bid - NB_MP) * 256 + threadIdx.x;
    if (i < 8 * L_ * H_) {
      float v = Wf[i];
      w2r[i] = v * v;
    }
  } else {
    cos_body(smem, bid - (NB_MP + NB_W), P, Q, cosM, sumpart, sum_q);
  }
}

// ---------------- K2: r14-verified packed arithmetic; RE-SCHEDULED phases:
// phase0 stages cosT+xP/xQ+tq/tp(ttq/ttp)+sums; phase1 runs middle (waves 0-4)
// CONCURRENT with the 160 middle-independent pr01 tail jobs (waves 5-7);
// phase2 runs the remaining 320 pr2345 jobs. Wave-uniform branching.
#define SG 4
struct OutsS {                      // 33664 B -> 4 blocks/CU (grid = 4/CU exact)
  float u[600];                     // cosT (512 floats used)
  float ttq[300], ttp[300];         // dedicated tq/tp (cosT stays live)
  float xP[SG][H_], xQ[SG][H_];
  float vmq[SG][H_], vmp[SG][H_], vxq[SG][H_], vxp[SG][H_];
  float sps[SG], sqs[SG];
};

__device__ __forceinline__ void outs_tail_job(const OutsS& S, int l, int pr,
                                              int si, int dir, int b, int s0,
                                              const float* __restrict__ w2r,
                                              float* __restrict__ out) {
  const float* xv = (pr & 1) ? S.xQ[si] : S.xP[si];
  const float* y;
  if (pr == 0) y = S.ttq;
  else if (pr == 1) y = S.ttp;
  else if (pr == 2) y = S.vmq[si];
  else if (pr == 3) y = S.vmp[si];
  else if (pr == 4) y = S.vxq[si];
  else y = S.vxp[si];
  const int wb_[6] = {0, 0, 4, 4, 6, 6};
  int widx = wb_[pr] + dir;
  const float* wp = w2r + (size_t)widx * (L_ * H_) + (size_t)l * H_;   // row layout
  float4v a1v = {0.f, 0.f, 0.f, 0.f};
  float4v a2v = {0.f, 0.f, 0.f, 0.f};
  float4v a3v = {0.f, 0.f, 0.f, 0.f};
  for (int h4 = 0; h4 < H_; h4 += 4) {
    float4v wv = *(const float4v*)&wp[h4];
    float4v xx = *(const float4v*)&xv[h4];
    float4v yy = *(const float4v*)&y[h4];
    float4v wx = wv * xx;
    float4v wy = wv * yy;
    a1v = wx * yy + a1v;
    a2v = wx * xx + a2v;
    a3v = wy * yy + a3v;
  }
  float a1 = (a1v.x + a1v.y) + (a1v.z + a1v.w);
  float a2 = (a2v.x + a2v.y) + (a2v.z + a2v.w);
  float a3 = (a3v.x + a3v.y) + (a3v.z + a3v.w);
  float den = fmaxf(sqrtf(a2) * sqrtf(a3), 1e-8f);   // EPS per _mp_cos
  float c = a1 / den;
  int s = s0 + si;
  size_t base = ((pr & 1) ? OUTQ_OFF : 0) + ((size_t)b * S_ + s) * ROW_;
  out[base + (size_t)widx * L_ + l] = c;
}

__global__ __launch_bounds__(512) void k2(const float* __restrict__ P,
                                          const float* __restrict__ Q,
                                          const float* __restrict__ w2r,
                                          const float* __restrict__ cosM,
                                          const float* __restrict__ sumpart,
                                          const float* __restrict__ sum_q,
                                          float* __restrict__ out) {
  extern __shared__ char smem[];
  OutsS& S = *(OutsS*)smem;
  int bid = blockIdx.x;
  // XCD swizzle: bd = (bid&7) + 8*((bid>>3)&7); sg = bid>>6
  int x = bid & 7, j = bid >> 3;
  int bd = x + 8 * (j & 7);
  int sg = j >> 3;
  int s0 = sg * SG;
  int b = bd >> 1, dir = bd & 1;
  int t = threadIdx.x;
  int tgt = dir ? 0 : S_ - 1;
  const float* Pb = P + (size_t)b * S_ * H2_ + dir * H_;
  const float* Qb = Q + (size_t)b * S_ * H2_ + dir * H_;
  // ---- phase 0: all staging
  float (*cosT)[8] = (float (*)[8])&S.u[0];     // 512 floats in u[600]
  const float* cm = cosM + (size_t)bd * S_ * S_;
  {
    int k = t >> 3, jj = t & 7, si = jj & 3;    // 512 entries, one per thread
    cosT[k][jj] = (jj < 4) ? cm[(size_t)k * S_ + s0 + si]
                           : cm[(size_t)(s0 + si) * S_ + k];
  }
  if (t < SG * 75) {                            // 300 b128 pairs
    int si = t / 75, c4 = t - si * 75;
    *(float4v*)&S.xP[si][4 * c4] = *(const float4v*)&Pb[(size_t)(s0 + si) * H2_ + 4 * c4];
    *(float4v*)&S.xQ[si][4 * c4] = *(const float4v*)&Qb[(size_t)(s0 + si) * H2_ + 4 * c4];
  } else if (t < 375) {                         // ttq: 75 float4
    int i = t - 300;
    *(float4v*)&S.ttq[4 * i] = *(const float4v*)&Qb[(size_t)tgt * H2_ + 4 * i];
  } else if (t < 450) {                         // ttp: 75 float4
    int i = t - 375;
    *(float4v*)&S.ttp[4 * i] = *(const float4v*)&Pb[(size_t)tgt * H2_ + 4 * i];
  } else if (t < 454) {
    float a = 0.f;
    int si = t - 450;
    for (int pg = 0; pg < 16; ++pg) a += sumpart[((size_t)bd * 16 + pg) * S_ + s0 + si];
    S.sps[si] = a;
  } else if (t < 458) {
    S.sqs[t - 454] = sum_q[bd * S_ + s0 + (t - 454)];
  }
  __syncthreads();
  // ---- phase 1: middle (waves 0-4) CONCURRENT with pr01 tail (waves 5-7)
  if (t < H_) {                                 // middle: h = t
    int h = t;
    float2v amp01 = {0.f, 0.f}, amp23 = {0.f, 0.f};
    float2v amq01 = {0.f, 0.f}, amq23 = {0.f, 0.f};
    float2v axp01 = {NEG_INF, NEG_INF}, axp23 = {NEG_INF, NEG_INF};
    float2v axq01 = {NEG_INF, NEG_INF}, axq23 = {NEG_INF, NEG_INF};
#pragma unroll 4
    for (int k = 0; k < S_; ++k) {
      float pv = Pb[(size_t)k * H2_ + h];
      float qv = Qb[(size_t)k * H2_ + h];
      float4v cc = *(const float4v*)&cosT[k][0];
      float4v cr = *(const float4v*)&cosT[k][4];
      float2v cc01 = {cc.x, cc.y}, cc23 = {cc.z, cc.w};
      float2v cr01 = {cr.x, cr.y}, cr23 = {cr.z, cr.w};
      float2v m0 = pv * cc01;
      amp01 += m0; axp01 = __builtin_elementwise_max(axp01, m0);
      float2v m1 = pv * cc23;
      amp23 += m1; axp23 = __builtin_elementwise_max(axp23, m1);
      float2v m2 = qv * cr01;
      amq01 += m2; axq01 = __builtin_elementwise_max(axq01, m2);
      float2v m3 = qv * cr23;
      amq23 += m3; axq23 = __builtin_elementwise_max(axq23, m3);
    }
    S.vmq[0][h] = amq01.x / S.sqs[0];
    S.vmq[1][h] = amq01.y / S.sqs[1];
    S.vmq[2][h] = amq23.x / S.sqs[2];
    S.vmq[3][h] = amq23.y / S.sqs[3];
    S.vmp[0][h] = amp01.x / S.sps[0];
    S.vmp[1][h] = amp01.y / S.sps[1];
    S.vmp[2][h] = amp23.x / S.sps[2];
    S.vmp[3][h] = amp23.y / S.sps[3];
    S.vxq[0][h] = axq01.x; S.vxq[1][h] = axq01.y;
    S.vxq[2][h] = axq23.x; S.vxq[3][h] = axq23.y;
    S.vxp[0][h] = axp01.x; S.vxp[1][h] = axp01.y;
    S.vxp[2][h] = axp23.x; S.vxp[3][h] = axp23.y;
  } else if (t >= 320 && t < 480) {             // 160 pr01 jobs (middle-indep)
    int jb = t - 320;
    int l = jb >> 3, g = jb & 7;
    int pr = g >> 2, si = g & 3;
    outs_tail_job(S, l, pr, si, dir, b, s0, w2r, out);
  }
  __syncthreads();
  // ---- phase 2: remaining 320 pr2345 jobs
  if (t < 320) {
    int l = t >> 4, g = t & 15;
    int pr = 2 + (g >> 2), si = g & 3;
    outs_tail_job(S, l, pr, si, dir, b, s0, w2r, out);
  }
}

extern "C" void kernel_launch(void* const* d_in, const int* in_sizes, int n_in,
                              void* d_out, int out_size, void* d_ws, size_t ws_size,
                              hipStream_t stream) {
  (void)out_size; (void)ws_size;
  int iw = 2;
  for (int i = 0; i < n_in; ++i) if (in_sizes[i] == 8 * L_ * H_) iw = i;
  int io[2] = {0, 1}, k = 0;
  for (int i = 0; i < n_in && k < 2; ++i) if (i != iw) io[k++] = i;
  const float* P  = (const float*)d_in[io[0]];
  const float* Q  = (const float*)d_in[io[1]];
  const float* Wf = (const float*)d_in[iw];
  float* out = (float*)d_out;

  float* ws = (float*)d_ws;             // ~1.52 MB
  float* w2r     = ws;                  // 48000
  float* cosM    = w2r + 48000;         // 262144
  float* sumpart = cosM + 262144;       // 65536 (64 bd * 16 pg * 64 q)
  float* sum_q   = sumpart + 65536;     // 4096

  size_t sh1 = sizeof(CosS) > sizeof(MaxpoolS) ? sizeof(CosS) : sizeof(MaxpoolS);
  k1<<<NB_MP + NB_W + NB_COS, 256, sh1, stream>>>(P, Q, Wf, w2r, cosM, sumpart, sum_q, out);
  k2<<<B_ * 2 * 16, 512, sizeof(OutsS), stream>>>(P, Q, w2r, cosM, sumpart, sum_q, out);
}

// Round 16
// 129.761 us; speedup vs baseline: 1.8248x; 1.0568x over previous
//
#include <hip/hip_runtime.h>

#define B_ 32
#define S_ 64
#define H_ 300
#define H2_ 600
#define L_ 20
#define ROW_ 160                    // 8 pieces * 20
#define OUTQ_OFF ((size_t)B_ * S_ * ROW_)
#define NEG_INF -3.402823466e38f

#define NB_MP 1280                  // 64 bd * 20 l   (dispatched first)
#define NB_W 188                    // 48000 / 256 rounded up
#define NB_CM 64                    // 1 cosM-MFMA block per bd

typedef __attribute__((ext_vector_type(8))) _Float16 half8v;   // 8 f16 = 4 VGPRs
typedef __attribute__((ext_vector_type(4))) _Float16 half4v;   // 4 f16 = 8 B
typedef __attribute__((ext_vector_type(4))) float float4v;
typedef __attribute__((ext_vector_type(2))) float float2v;

#define HP 72                       // padded fp16 row: 144 B, 16-B aligned f16x8 groups

// ---------------- maxpool block (byte-identical to r15-verified version)
struct MaxpoolS {                   // 21168 B
  _Float16 ph[S_][HP];
  _Float16 qh[S_][HP];
  float w1s[H_];
  float pn2[S_], qn2[S_];
  float colp[4][S_];
};

__device__ __forceinline__ void maxpool_body(char* smem, int bid,
                                             const float* __restrict__ P,
                                             const float* __restrict__ Q,
                                             const float* __restrict__ Wf,
                                             float* __restrict__ out) {
  MaxpoolS& S = *(MaxpoolS*)smem;
  // XCD swizzle: bd = (bid&7) + 8*((bid>>3)&7); l = bid>>6
  int x = bid & 7, j = bid >> 3;
  int bd = x + 8 * (j & 7);
  int l = j >> 3;
  int b = bd >> 1, dir = bd & 1;
  int t = threadIdx.x;
  int w = t >> 6, lane = t & 63, quad = lane >> 4, col = lane & 15;
  const float* wg = Wf + (size_t)(2 + dir) * L_ * H_ + (size_t)l * H_;
  if (t < 75) {
    float4v v = *(const float4v*)&wg[4 * t];
    float4v a = {fabsf(v.x), fabsf(v.y), fabsf(v.z), fabsf(v.w)};
    *(float4v*)&S.w1s[4 * t] = a;
  }
  const float* Pb = P + (size_t)b * S_ * H2_ + dir * H_;
  const float* Qb = Q + (size_t)b * S_ * H2_ + dir * H_;
  float4v acc[4];
#pragma unroll
  for (int qt = 0; qt < 4; ++qt) acc[qt] = (float4v){0.f, 0.f, 0.f, 0.f};
  float np2a[4] = {0.f, 0.f, 0.f, 0.f};
  float nq2a[4] = {0.f, 0.f, 0.f, 0.f};
  for (int h0 = 0; h0 < H_; h0 += 64) {          // 5 chunks (last zero-padded)
    __syncthreads();
#pragma unroll
    for (int jj = 0; jj < 4; ++jj) {             // float4 staging: 4 iters/chunk
      int idx = t + 256 * jj;
      int s = idx >> 4, c4 = idx & 15;
      int h = h0 + 4 * c4;
      float4v pv = {0.f, 0.f, 0.f, 0.f}, qv = {0.f, 0.f, 0.f, 0.f};
      if (h < 297) {                             // full group valid (h+3 <= 299)
        float4v wv = *(const float4v*)&S.w1s[h];
        float4v p4 = *(const float4v*)&Pb[(size_t)s * H2_ + h];
        float4v q4 = *(const float4v*)&Qb[(size_t)s * H2_ + h];
        pv = p4 * wv;
        qv = q4 * wv;
      }
      half4v phv = __builtin_convertvector(pv, half4v);
      half4v qhv = __builtin_convertvector(qv, half4v);
      *(half4v*)&S.ph[s][4 * c4] = phv;
      *(half4v*)&S.qh[s][4 * c4] = qhv;
      // norms from the SAME fp16 values (consistent with MFMA numerator)
      float4v pf = __builtin_convertvector(phv, float4v);
      float4v qf = __builtin_convertvector(qhv, float4v);
      np2a[jj] += pf.x * pf.x + pf.y * pf.y + pf.z * pf.z + pf.w * pf.w;
      nq2a[jj] += qf.x * qf.x + qf.y * qf.y + qf.z * qf.z + qf.w * qf.w;
    }
    __syncthreads();
#pragma unroll
    for (int ks = 0; ks < 2; ++ks) {
      half8v ah = *(const half8v*)&S.ph[16 * w + col][ks * 32 + quad * 8];
#pragma unroll
      for (int qt = 0; qt < 4; ++qt) {
        half8v bh = *(const half8v*)&S.qh[16 * qt + col][ks * 32 + quad * 8];
        acc[qt] = __builtin_amdgcn_mfma_f32_16x16x32_f16(ah, bh, acc[qt], 0, 0, 0);
      }
    }
  }
#pragma unroll
  for (int jj = 0; jj < 4; ++jj) {
    float a = np2a[jj], bb = nq2a[jj];
#pragma unroll
    for (int m = 1; m < 16; m <<= 1) {
      a += __shfl_xor(a, m);
      bb += __shfl_xor(bb, m);
    }
    if ((t & 15) == 0) {
      int s = (t >> 4) + 16 * jj;
      S.pn2[s] = a;
      S.qn2[s] = bb;
    }
  }
  __syncthreads();
  // C/D: row = quad*4+r (p_local), col = lane&15 (q_local) [m89/m91 verified]
  float pnv[4];
#pragma unroll
  for (int r = 0; r < 4; ++r) pnv[r] = sqrtf(S.pn2[16 * w + quad * 4 + r]);
  float rowm[4] = {NEG_INF, NEG_INF, NEG_INF, NEG_INF};
#pragma unroll
  for (int qt = 0; qt < 4; ++qt) {
    float qnv = sqrtf(S.qn2[16 * qt + col]);
    float cmv = NEG_INF;
#pragma unroll
    for (int r = 0; r < 4; ++r) {
      float c = acc[qt][r] / (pnv[r] * qnv);    // no EPS in reference maxpool
      rowm[r] = fmaxf(rowm[r], c);
      cmv = fmaxf(cmv, c);
    }
    cmv = fmaxf(cmv, __shfl_xor(cmv, 16));
    cmv = fmaxf(cmv, __shfl_xor(cmv, 32));
    if (quad == 0) S.colp[w][16 * qt + col] = cmv;
  }
#pragma unroll
  for (int m = 1; m < 16; m <<= 1)
#pragma unroll
    for (int r = 0; r < 4; ++r) rowm[r] = fmaxf(rowm[r], __shfl_xor(rowm[r], m));
  if (col == 0) {
#pragma unroll
    for (int r = 0; r < 4; ++r) {
      int p = 16 * w + quad * 4 + r;
      out[((size_t)b * S_ + p) * ROW_ + (2 + dir) * L_ + l] = rowm[r];
    }
  }
  __syncthreads();
  if (t < S_) {
    float m0 = fmaxf(fmaxf(S.colp[0][t], S.colp[1][t]), fmaxf(S.colp[2][t], S.colp[3][t]));
    out[OUTQ_OFF + ((size_t)b * S_ + t) * ROW_ + (2 + dir) * L_ + l] = m0;
  }
}

// ---------------- cosM block: maxpool machinery with w==1; writes cosM +
// sum_q (row sums, shfl over col) + sum_p (col sums, quad-shfl + colp LDS).
// Replaces 1024 scalar-VALU cos blocks with 64 MFMA blocks. fp16 dot errors
// ~1e-3 (same as verified maxpool); attentive outputs are cosine-normalized
// so the sum-scale errors cancel.
struct CosmS {                      // 19968 B (< MaxpoolS)
  _Float16 ph[S_][HP];
  _Float16 qh[S_][HP];
  float pn2[S_], qn2[S_];
  float colp[4][S_];
};

__device__ __forceinline__ void cosm_body(char* smem, int bd,
                                          const float* __restrict__ P,
                                          const float* __restrict__ Q,
                                          float* __restrict__ cosM,
                                          float* __restrict__ sum_p,
                                          float* __restrict__ sum_q) {
  CosmS& S = *(CosmS*)smem;
  int b = bd >> 1, dir = bd & 1;
  int t = threadIdx.x;
  int w = t >> 6, lane = t & 63, quad = lane >> 4, col = lane & 15;
  const float* Pb = P + (size_t)b * S_ * H2_ + dir * H_;
  const float* Qb = Q + (size_t)b * S_ * H2_ + dir * H_;
  float4v acc[4];
#pragma unroll
  for (int qt = 0; qt < 4; ++qt) acc[qt] = (float4v){0.f, 0.f, 0.f, 0.f};
  float np2a[4] = {0.f, 0.f, 0.f, 0.f};
  float nq2a[4] = {0.f, 0.f, 0.f, 0.f};
  for (int h0 = 0; h0 < H_; h0 += 64) {          // 5 chunks (last zero-padded)
    __syncthreads();
#pragma unroll
    for (int jj = 0; jj < 4; ++jj) {
      int idx = t + 256 * jj;
      int s = idx >> 4, c4 = idx & 15;
      int h = h0 + 4 * c4;
      float4v pv = {0.f, 0.f, 0.f, 0.f}, qv = {0.f, 0.f, 0.f, 0.f};
      if (h < 297) {
        pv = *(const float4v*)&Pb[(size_t)s * H2_ + h];
        qv = *(const float4v*)&Qb[(size_t)s * H2_ + h];
      }
      half4v phv = __builtin_convertvector(pv, half4v);
      half4v qhv = __builtin_convertvector(qv, half4v);
      *(half4v*)&S.ph[s][4 * c4] = phv;
      *(half4v*)&S.qh[s][4 * c4] = qhv;
      float4v pf = __builtin_convertvector(phv, float4v);
      float4v qf = __builtin_convertvector(qhv, float4v);
      np2a[jj] += pf.x * pf.x + pf.y * pf.y + pf.z * pf.z + pf.w * pf.w;
      nq2a[jj] += qf.x * qf.x + qf.y * qf.y + qf.z * qf.z + qf.w * qf.w;
    }
    __syncthreads();
#pragma unroll
    for (int ks = 0; ks < 2; ++ks) {
      half8v ah = *(const half8v*)&S.ph[16 * w + col][ks * 32 + quad * 8];
#pragma unroll
      for (int qt = 0; qt < 4; ++qt) {
        half8v bh = *(const half8v*)&S.qh[16 * qt + col][ks * 32 + quad * 8];
        acc[qt] = __builtin_amdgcn_mfma_f32_16x16x32_f16(ah, bh, acc[qt], 0, 0, 0);
      }
    }
  }
#pragma unroll
  for (int jj = 0; jj < 4; ++jj) {
    float a = np2a[jj], bb = nq2a[jj];
#pragma unroll
    for (int m = 1; m < 16; m <<= 1) {
      a += __shfl_xor(a, m);
      bb += __shfl_xor(bb, m);
    }
    if ((t & 15) == 0) {
      int s = (t >> 4) + 16 * jj;
      S.pn2[s] = a;
      S.qn2[s] = bb;
    }
  }
  __syncthreads();
  float pnv[4];
#pragma unroll
  for (int r = 0; r < 4; ++r) pnv[r] = sqrtf(S.pn2[16 * w + quad * 4 + r]);
  float* cm = cosM + (size_t)bd * S_ * S_;
  float rows_[4] = {0.f, 0.f, 0.f, 0.f};
  float cols_[4] = {0.f, 0.f, 0.f, 0.f};
#pragma unroll
  for (int qt = 0; qt < 4; ++qt) {
    float qnv = sqrtf(S.qn2[16 * qt + col]);
#pragma unroll
    for (int r = 0; r < 4; ++r) {
      float c = acc[qt][r] / (pnv[r] * qnv);
      cm[(size_t)(16 * w + quad * 4 + r) * S_ + 16 * qt + col] = c;
      rows_[r] += c;
      cols_[qt] += c;
    }
  }
#pragma unroll
  for (int m = 1; m < 16; m <<= 1)
#pragma unroll
    for (int r = 0; r < 4; ++r) rows_[r] += __shfl_xor(rows_[r], m);
  if (col == 0) {
#pragma unroll
    for (int r = 0; r < 4; ++r)
      sum_q[bd * S_ + 16 * w + quad * 4 + r] = rows_[r];
  }
#pragma unroll
  for (int qt = 0; qt < 4; ++qt) {
    cols_[qt] += __shfl_xor(cols_[qt], 16);
    cols_[qt] += __shfl_xor(cols_[qt], 32);
  }
  if (quad == 0) {
#pragma unroll
    for (int qt = 0; qt < 4; ++qt) S.colp[w][16 * qt + col] = cols_[qt];
  }
  __syncthreads();
  if (t < S_)
    sum_p[bd * S_ + t] = S.colp[0][t] + S.colp[1][t] + S.colp[2][t] + S.colp[3][t];
}

// ---------------- K1: maxpool (1280) + w^2 (188) + cosM (64), one launch.
__global__ __launch_bounds__(256) void k1(const float* __restrict__ P,
                                          const float* __restrict__ Q,
                                          const float* __restrict__ Wf,
                                          float* __restrict__ w2r,
                                          float* __restrict__ cosM,
                                          float* __restrict__ sum_p,
                                          float* __restrict__ sum_q,
                                          float* __restrict__ out) {
  extern __shared__ char smem[];
  int bid = blockIdx.x;
  if (bid < NB_MP) {
    maxpool_body(smem, bid, P, Q, Wf, out);
  } else if (bid < NB_MP + NB_W) {
    int i = (bid - NB_MP) * 256 + threadIdx.x;
    if (i < 8 * L_ * H_) {
      float v = Wf[i];
      w2r[i] = v * v;
    }
  } else {
    cosm_body(smem, bid - (NB_MP + NB_W), P, Q, cosM, sum_p, sum_q);
  }
}

// ---------------- K2: EXACT r15-verified version; only change: sps read
// directly from sum_p (no sumpart aggregation).
#define SG 4
struct OutsS {                      // 33664 B
  float u[600];                     // cosT (512 floats used)
  float ttq[300], ttp[300];         // dedicated tq/tp (cosT stays live)
  float xP[SG][H_], xQ[SG][H_];
  float vmq[SG][H_], vmp[SG][H_], vxq[SG][H_], vxp[SG][H_];
  float sps[SG], sqs[SG];
};

__device__ __forceinline__ void outs_tail_job(const OutsS& S, int l, int pr,
                                              int si, int dir, int b, int s0,
                                              const float* __restrict__ w2r,
                                              float* __restrict__ out) {
  const float* xv = (pr & 1) ? S.xQ[si] : S.xP[si];
  const float* y;
  if (pr == 0) y = S.ttq;
  else if (pr == 1) y = S.ttp;
  else if (pr == 2) y = S.vmq[si];
  else if (pr == 3) y = S.vmp[si];
  else if (pr == 4) y = S.vxq[si];
  else y = S.vxp[si];
  const int wb_[6] = {0, 0, 4, 4, 6, 6};
  int widx = wb_[pr] + dir;
  const float* wp = w2r + (size_t)widx * (L_ * H_) + (size_t)l * H_;   // row layout
  float4v a1v = {0.f, 0.f, 0.f, 0.f};
  float4v a2v = {0.f, 0.f, 0.f, 0.f};
  float4v a3v = {0.f, 0.f, 0.f, 0.f};
  for (int h4 = 0; h4 < H_; h4 += 4) {
    float4v wv = *(const float4v*)&wp[h4];
    float4v xx = *(const float4v*)&xv[h4];
    float4v yy = *(const float4v*)&y[h4];
    float4v wx = wv * xx;
    float4v wy = wv * yy;
    a1v = wx * yy + a1v;
    a2v = wx * xx + a2v;
    a3v = wy * yy + a3v;
  }
  float a1 = (a1v.x + a1v.y) + (a1v.z + a1v.w);
  float a2 = (a2v.x + a2v.y) + (a2v.z + a2v.w);
  float a3 = (a3v.x + a3v.y) + (a3v.z + a3v.w);
  float den = fmaxf(sqrtf(a2) * sqrtf(a3), 1e-8f);   // EPS per _mp_cos
  float c = a1 / den;
  int s = s0 + si;
  size_t base = ((pr & 1) ? OUTQ_OFF : 0) + ((size_t)b * S_ + s) * ROW_;
  out[base + (size_t)widx * L_ + l] = c;
}

__global__ __launch_bounds__(512) void k2(const float* __restrict__ P,
                                          const float* __restrict__ Q,
                                          const float* __restrict__ w2r,
                                          const float* __restrict__ cosM,
                                          const float* __restrict__ sum_p,
                                          const float* __restrict__ sum_q,
                                          float* __restrict__ out) {
  extern __shared__ char smem[];
  OutsS& S = *(OutsS*)smem;
  int bid = blockIdx.x;
  // XCD swizzle: bd = (bid&7) + 8*((bid>>3)&7); sg = bid>>6
  int x = bid & 7, j = bid >> 3;
  int bd = x + 8 * (j & 7);
  int sg = j >> 3;
  int s0 = sg * SG;
  int b = bd >> 1, dir = bd & 1;
  int t = threadIdx.x;
  int tgt = dir ? 0 : S_ - 1;
  const float* Pb = P + (size_t)b * S_ * H2_ + dir * H_;
  const float* Qb = Q + (size_t)b * S_ * H2_ + dir * H_;
  // ---- phase 0: all staging
  float (*cosT)[8] = (float (*)[8])&S.u[0];     // 512 floats in u[600]
  const float* cm = cosM + (size_t)bd * S_ * S_;
  {
    int k = t >> 3, jj = t & 7, si = jj & 3;    // 512 entries, one per thread
    cosT[k][jj] = (jj < 4) ? cm[(size_t)k * S_ + s0 + si]
                           : cm[(size_t)(s0 + si) * S_ + k];
  }
  if (t < SG * 75) {                            // 300 b128 pairs
    int si = t / 75, c4 = t - si * 75;
    *(float4v*)&S.xP[si][4 * c4] = *(const float4v*)&Pb[(size_t)(s0 + si) * H2_ + 4 * c4];
    *(float4v*)&S.xQ[si][4 * c4] = *(const float4v*)&Qb[(size_t)(s0 + si) * H2_ + 4 * c4];
  } else if (t < 375) {                         // ttq: 75 float4
    int i = t - 300;
    *(float4v*)&S.ttq[4 * i] = *(const float4v*)&Qb[(size_t)tgt * H2_ + 4 * i];
  } else if (t < 450) {                         // ttp: 75 float4
    int i = t - 375;
    *(float4v*)&S.ttp[4 * i] = *(const float4v*)&Pb[(size_t)tgt * H2_ + 4 * i];
  } else if (t < 454) {
    S.sps[t - 450] = sum_p[bd * S_ + s0 + (t - 450)];
  } else if (t < 458) {
    S.sqs[t - 454] = sum_q[bd * S_ + s0 + (t - 454)];
  }
  __syncthreads();
  // ---- phase 1: middle (waves 0-4) CONCURRENT with pr01 tail (waves 5-7)
  if (t < H_) {                                 // middle: h = t
    int h = t;
    float2v amp01 = {0.f, 0.f}, amp23 = {0.f, 0.f};
    float2v amq01 = {0.f, 0.f}, amq23 = {0.f, 0.f};
    float2v axp01 = {NEG_INF, NEG_INF}, axp23 = {NEG_INF, NEG_INF};
    float2v axq01 = {NEG_INF, NEG_INF}, axq23 = {NEG_INF, NEG_INF};
#pragma unroll 4
    for (int k = 0; k < S_; ++k) {
      float pv = Pb[(size_t)k * H2_ + h];
      float qv = Qb[(size_t)k * H2_ + h];
      float4v cc = *(const float4v*)&cosT[k][0];
      float4v cr = *(const float4v*)&cosT[k][4];
      float2v cc01 = {cc.x, cc.y}, cc23 = {cc.z, cc.w};
      float2v cr01 = {cr.x, cr.y}, cr23 = {cr.z, cr.w};
      float2v m0 = pv * cc01;
      amp01 += m0; axp01 = __builtin_elementwise_max(axp01, m0);
      float2v m1 = pv * cc23;
      amp23 += m1; axp23 = __builtin_elementwise_max(axp23, m1);
      float2v m2 = qv * cr01;
      amq01 += m2; axq01 = __builtin_elementwise_max(axq01, m2);
      float2v m3 = qv * cr23;
      amq23 += m3; axq23 = __builtin_elementwise_max(axq23, m3);
    }
    S.vmq[0][h] = amq01.x / S.sqs[0];
    S.vmq[1][h] = amq01.y / S.sqs[1];
    S.vmq[2][h] = amq23.x / S.sqs[2];
    S.vmq[3][h] = amq23.y / S.sqs[3];
    S.vmp[0][h] = amp01.x / S.sps[0];
    S.vmp[1][h] = amp01.y / S.sps[1];
    S.vmp[2][h] = amp23.x / S.sps[2];
    S.vmp[3][h] = amp23.y / S.sps[3];
    S.vxq[0][h] = axq01.x; S.vxq[1][h] = axq01.y;
    S.vxq[2][h] = axq23.x; S.vxq[3][h] = axq23.y;
    S.vxp[0][h] = axp01.x; S.vxp[1][h] = axp01.y;
    S.vxp[2][h] = axp23.x; S.vxp[3][h] = axp23.y;
  } else if (t >= 320 && t < 480) {             // 160 pr01 jobs (middle-indep)
    int jb = t - 320;
    int l = jb >> 3, g = jb & 7;
    int pr = g >> 2, si = g & 3;
    outs_tail_job(S, l, pr, si, dir, b, s0, w2r, out);
  }
  __syncthreads();
  // ---- phase 2: remaining 320 pr2345 jobs
  if (t < 320) {
    int l = t >> 4, g = t & 15;
    int pr = 2 + (g >> 2), si = g & 3;
    outs_tail_job(S, l, pr, si, dir, b, s0, w2r, out);
  }
}

extern "C" void kernel_launch(void* const* d_in, const int* in_sizes, int n_in,
                              void* d_out, int out_size, void* d_ws, size_t ws_size,
                              hipStream_t stream) {
  (void)out_size; (void)ws_size;
  int iw = 2;
  for (int i = 0; i < n_in; ++i) if (in_sizes[i] == 8 * L_ * H_) iw = i;
  int io[2] = {0, 1}, k = 0;
  for (int i = 0; i < n_in && k < 2; ++i) if (i != iw) io[k++] = i;
  const float* P  = (const float*)d_in[io[0]];
  const float* Q  = (const float*)d_in[io[1]];
  const float* Wf = (const float*)d_in[iw];
  float* out = (float*)d_out;

  float* ws = (float*)d_ws;             // ~1.27 MB
  float* w2r     = ws;                  // 48000
  float* cosM    = w2r + 48000;         // 262144
  float* sum_p   = cosM + 262144;       // 4096
  float* sum_q   = sum_p + 4096;        // 4096

  size_t sh1 = sizeof(MaxpoolS);        // CosmS (19968) < MaxpoolS (21168)
  k1<<<NB_MP + NB_W + NB_CM, 256, sh1, stream>>>(P, Q, Wf, w2r, cosM, sum_p, sum_q, out);
  k2<<<B_ * 2 * 16, 512, sizeof(OutsS), stream>>>(P, Q, w2r, cosM, sum_p, sum_q, out);
}

// Round 17
// 124.785 us; speedup vs baseline: 1.8976x; 1.0399x over previous
//
#include <hip/hip_runtime.h>

#define B_ 32
#define S_ 64
#define H_ 300
#define H2_ 600
#define L_ 20
#define ROW_ 160                    // 8 pieces * 20
#define OUTQ_OFF ((size_t)B_ * S_ * ROW_)
#define NEG_INF -3.402823466e38f

#define NB_MP 640                   // 64 bd * 10 l-pairs (dispatched first)
#define NB_W 188                    // 48000 / 256 rounded up
#define NB_CM 64                    // 1 cosM-MFMA block per bd

typedef __attribute__((ext_vector_type(8))) _Float16 half8v;   // 8 f16 = 4 VGPRs
typedef __attribute__((ext_vector_type(4))) _Float16 half4v;   // 4 f16 = 8 B
typedef __attribute__((ext_vector_type(4))) float float4v;
typedef __attribute__((ext_vector_type(2))) float float2v;

#define HP 72                       // padded fp16 row: 144 B, 16-B aligned f16x8 groups

// ---------------- maxpool block: TWO l per block. P/Q loaded ONCE, scaled by
// both w rows into two LDS buffer pairs in one staging pass -> still 2
// barriers/chunk, half the global-load instructions and L2 traffic vs r16.
// Per-output arithmetic is bit-identical to the r16-verified body.
struct MaxpoolS {                   // 42368 B -> 3 blocks/CU
  _Float16 ph[2][S_][HP];
  _Float16 qh[2][S_][HP];
  float w1s[2][304];
  float pn2[2][S_], qn2[2][S_];
  float colp[2][4][S_];
};

__device__ __forceinline__ void maxpool_body(char* smem, int bid,
                                             const float* __restrict__ P,
                                             const float* __restrict__ Q,
                                             const float* __restrict__ Wf,
                                             float* __restrict__ out) {
  MaxpoolS& S = *(MaxpoolS*)smem;
  // XCD swizzle: bd = (bid&7) + 8*((bid>>3)&7); lp = bid>>6 in [0,10)
  int x = bid & 7, j = bid >> 3;
  int bd = x + 8 * (j & 7);
  int lp = j >> 3;
  int l0 = 2 * lp;
  int b = bd >> 1, dir = bd & 1;
  int t = threadIdx.x;
  int w = t >> 6, lane = t & 63, quad = lane >> 4, col = lane & 15;
  const float* wgb = Wf + (size_t)(2 + dir) * L_ * H_ + (size_t)l0 * H_;
  if (t < 150) {                    // 2 rows x 75 float4
    int row = t / 75, i = t - row * 75;
    float4v v = *(const float4v*)&wgb[(size_t)row * H_ + 4 * i];
    float4v a = {fabsf(v.x), fabsf(v.y), fabsf(v.z), fabsf(v.w)};
    *(float4v*)&S.w1s[row][4 * i] = a;
  }
  const float* Pb = P + (size_t)b * S_ * H2_ + dir * H_;
  const float* Qb = Q + (size_t)b * S_ * H2_ + dir * H_;
  float4v acc[2][4];
#pragma unroll
  for (int l2 = 0; l2 < 2; ++l2)
#pragma unroll
    for (int qt = 0; qt < 4; ++qt) acc[l2][qt] = (float4v){0.f, 0.f, 0.f, 0.f};
  float np2a[2][4] = {{0.f, 0.f, 0.f, 0.f}, {0.f, 0.f, 0.f, 0.f}};
  float nq2a[2][4] = {{0.f, 0.f, 0.f, 0.f}, {0.f, 0.f, 0.f, 0.f}};
  for (int h0 = 0; h0 < H_; h0 += 64) {          // 5 chunks (last zero-padded)
    __syncthreads();
#pragma unroll
    for (int jj = 0; jj < 4; ++jj) {             // float4 staging: 4 iters/chunk
      int idx = t + 256 * jj;
      int s = idx >> 4, c4 = idx & 15;
      int h = h0 + 4 * c4;
      float4v pv0 = {0.f, 0.f, 0.f, 0.f}, qv0 = {0.f, 0.f, 0.f, 0.f};
      float4v pv1 = {0.f, 0.f, 0.f, 0.f}, qv1 = {0.f, 0.f, 0.f, 0.f};
      if (h < 297) {                             // full group valid (h+3 <= 299)
        float4v p4 = *(const float4v*)&Pb[(size_t)s * H2_ + h];
        float4v q4 = *(const float4v*)&Qb[(size_t)s * H2_ + h];
        float4v w0 = *(const float4v*)&S.w1s[0][h];
        float4v w1 = *(const float4v*)&S.w1s[1][h];
        pv0 = p4 * w0; qv0 = q4 * w0;
        pv1 = p4 * w1; qv1 = q4 * w1;
      }
      half4v ph0 = __builtin_convertvector(pv0, half4v);
      half4v qh0 = __builtin_convertvector(qv0, half4v);
      half4v ph1 = __builtin_convertvector(pv1, half4v);
      half4v qh1 = __builtin_convertvector(qv1, half4v);
      *(half4v*)&S.ph[0][s][4 * c4] = ph0;
      *(half4v*)&S.qh[0][s][4 * c4] = qh0;
      *(half4v*)&S.ph[1][s][4 * c4] = ph1;
      *(half4v*)&S.qh[1][s][4 * c4] = qh1;
      // norms from the SAME fp16 values (consistent with MFMA numerator)
      float4v pf0 = __builtin_convertvector(ph0, float4v);
      float4v qf0 = __builtin_convertvector(qh0, float4v);
      float4v pf1 = __builtin_convertvector(ph1, float4v);
      float4v qf1 = __builtin_convertvector(qh1, float4v);
      np2a[0][jj] += pf0.x * pf0.x + pf0.y * pf0.y + pf0.z * pf0.z + pf0.w * pf0.w;
      nq2a[0][jj] += qf0.x * qf0.x + qf0.y * qf0.y + qf0.z * qf0.z + qf0.w * qf0.w;
      np2a[1][jj] += pf1.x * pf1.x + pf1.y * pf1.y + pf1.z * pf1.z + pf1.w * pf1.w;
      nq2a[1][jj] += qf1.x * qf1.x + qf1.y * qf1.y + qf1.z * qf1.z + qf1.w * qf1.w;
    }
    __syncthreads();
#pragma unroll
    for (int l2 = 0; l2 < 2; ++l2) {
#pragma unroll
      for (int ks = 0; ks < 2; ++ks) {
        half8v ah = *(const half8v*)&S.ph[l2][16 * w + col][ks * 32 + quad * 8];
#pragma unroll
        for (int qt = 0; qt < 4; ++qt) {
          half8v bh = *(const half8v*)&S.qh[l2][16 * qt + col][ks * 32 + quad * 8];
          acc[l2][qt] = __builtin_amdgcn_mfma_f32_16x16x32_f16(ah, bh, acc[l2][qt], 0, 0, 0);
        }
      }
    }
  }
#pragma unroll
  for (int l2 = 0; l2 < 2; ++l2)
#pragma unroll
    for (int jj = 0; jj < 4; ++jj) {
      float a = np2a[l2][jj], bb = nq2a[l2][jj];
#pragma unroll
      for (int m = 1; m < 16; m <<= 1) {
        a += __shfl_xor(a, m);
        bb += __shfl_xor(bb, m);
      }
      if ((t & 15) == 0) {
        int s = (t >> 4) + 16 * jj;
        S.pn2[l2][s] = a;
        S.qn2[l2][s] = bb;
      }
    }
  __syncthreads();
  // C/D: row = quad*4+r (p_local), col = lane&15 (q_local) [m89/m91 verified]
#pragma unroll
  for (int l2 = 0; l2 < 2; ++l2) {
    float pnv[4];
#pragma unroll
    for (int r = 0; r < 4; ++r) pnv[r] = sqrtf(S.pn2[l2][16 * w + quad * 4 + r]);
    float rowm[4] = {NEG_INF, NEG_INF, NEG_INF, NEG_INF};
#pragma unroll
    for (int qt = 0; qt < 4; ++qt) {
      float qnv = sqrtf(S.qn2[l2][16 * qt + col]);
      float cmv = NEG_INF;
#pragma unroll
      for (int r = 0; r < 4; ++r) {
        float c = acc[l2][qt][r] / (pnv[r] * qnv);   // no EPS in reference maxpool
        rowm[r] = fmaxf(rowm[r], c);
        cmv = fmaxf(cmv, c);
      }
      cmv = fmaxf(cmv, __shfl_xor(cmv, 16));
      cmv = fmaxf(cmv, __shfl_xor(cmv, 32));
      if (quad == 0) S.colp[l2][w][16 * qt + col] = cmv;
    }
#pragma unroll
    for (int m = 1; m < 16; m <<= 1)
#pragma unroll
      for (int r = 0; r < 4; ++r) rowm[r] = fmaxf(rowm[r], __shfl_xor(rowm[r], m));
    if (col == 0) {
#pragma unroll
      for (int r = 0; r < 4; ++r) {
        int p = 16 * w + quad * 4 + r;
        out[((size_t)b * S_ + p) * ROW_ + (2 + dir) * L_ + (l0 + l2)] = rowm[r];
      }
    }
  }
  __syncthreads();
  if (t < 128) {
    int l2 = t >> 6, s = t & 63;
    float m0 = fmaxf(fmaxf(S.colp[l2][0][s], S.colp[l2][1][s]),
                     fmaxf(S.colp[l2][2][s], S.colp[l2][3][s]));
    out[OUTQ_OFF + ((size_t)b * S_ + s) * ROW_ + (2 + dir) * L_ + (l0 + l2)] = m0;
  }
}

// ---------------- cosM block (byte-identical to r16-verified version)
struct CosmS {                      // 19968 B
  _Float16 ph[S_][HP];
  _Float16 qh[S_][HP];
  float pn2[S_], qn2[S_];
  float colp[4][S_];
};

__device__ __forceinline__ void cosm_body(char* smem, int bd,
                                          const float* __restrict__ P,
                                          const float* __restrict__ Q,
                                          float* __restrict__ cosM,
                                          float* __restrict__ sum_p,
                                          float* __restrict__ sum_q) {
  CosmS& S = *(CosmS*)smem;
  int b = bd >> 1, dir = bd & 1;
  int t = threadIdx.x;
  int w = t >> 6, lane = t & 63, quad = lane >> 4, col = lane & 15;
  const float* Pb = P + (size_t)b * S_ * H2_ + dir * H_;
  const float* Qb = Q + (size_t)b * S_ * H2_ + dir * H_;
  float4v acc[4];
#pragma unroll
  for (int qt = 0; qt < 4; ++qt) acc[qt] = (float4v){0.f, 0.f, 0.f, 0.f};
  float np2a[4] = {0.f, 0.f, 0.f, 0.f};
  float nq2a[4] = {0.f, 0.f, 0.f, 0.f};
  for (int h0 = 0; h0 < H_; h0 += 64) {          // 5 chunks (last zero-padded)
    __syncthreads();
#pragma unroll
    for (int jj = 0; jj < 4; ++jj) {
      int idx = t + 256 * jj;
      int s = idx >> 4, c4 = idx & 15;
      int h = h0 + 4 * c4;
      float4v pv = {0.f, 0.f, 0.f, 0.f}, qv = {0.f, 0.f, 0.f, 0.f};
      if (h < 297) {
        pv = *(const float4v*)&Pb[(size_t)s * H2_ + h];
        qv = *(const float4v*)&Qb[(size_t)s * H2_ + h];
      }
      half4v phv = __builtin_convertvector(pv, half4v);
      half4v qhv = __builtin_convertvector(qv, half4v);
      *(half4v*)&S.ph[s][4 * c4] = phv;
      *(half4v*)&S.qh[s][4 * c4] = qhv;
      float4v pf = __builtin_convertvector(phv, float4v);
      float4v qf = __builtin_convertvector(qhv, float4v);
      np2a[jj] += pf.x * pf.x + pf.y * pf.y + pf.z * pf.z + pf.w * pf.w;
      nq2a[jj] += qf.x * qf.x + qf.y * qf.y + qf.z * qf.z + qf.w * qf.w;
    }
    __syncthreads();
#pragma unroll
    for (int ks = 0; ks < 2; ++ks) {
      half8v ah = *(const half8v*)&S.ph[16 * w + col][ks * 32 + quad * 8];
#pragma unroll
      for (int qt = 0; qt < 4; ++qt) {
        half8v bh = *(const half8v*)&S.qh[16 * qt + col][ks * 32 + quad * 8];
        acc[qt] = __builtin_amdgcn_mfma_f32_16x16x32_f16(ah, bh, acc[qt], 0, 0, 0);
      }
    }
  }
#pragma unroll
  for (int jj = 0; jj < 4; ++jj) {
    float a = np2a[jj], bb = nq2a[jj];
#pragma unroll
    for (int m = 1; m < 16; m <<= 1) {
      a += __shfl_xor(a, m);
      bb += __shfl_xor(bb, m);
    }
    if ((t & 15) == 0) {
      int s = (t >> 4) + 16 * jj;
      S.pn2[s] = a;
      S.qn2[s] = bb;
    }
  }
  __syncthreads();
  float pnv[4];
#pragma unroll
  for (int r = 0; r < 4; ++r) pnv[r] = sqrtf(S.pn2[16 * w + quad * 4 + r]);
  float* cm = cosM + (size_t)bd * S_ * S_;
  float rows_[4] = {0.f, 0.f, 0.f, 0.f};
  float cols_[4] = {0.f, 0.f, 0.f, 0.f};
#pragma unroll
  for (int qt = 0; qt < 4; ++qt) {
    float qnv = sqrtf(S.qn2[16 * qt + col]);
#pragma unroll
    for (int r = 0; r < 4; ++r) {
      float c = acc[qt][r] / (pnv[r] * qnv);
      cm[(size_t)(16 * w + quad * 4 + r) * S_ + 16 * qt + col] = c;
      rows_[r] += c;
      cols_[qt] += c;
    }
  }
#pragma unroll
  for (int m = 1; m < 16; m <<= 1)
#pragma unroll
    for (int r = 0; r < 4; ++r) rows_[r] += __shfl_xor(rows_[r], m);
  if (col == 0) {
#pragma unroll
    for (int r = 0; r < 4; ++r)
      sum_q[bd * S_ + 16 * w + quad * 4 + r] = rows_[r];
  }
#pragma unroll
  for (int qt = 0; qt < 4; ++qt) {
    cols_[qt] += __shfl_xor(cols_[qt], 16);
    cols_[qt] += __shfl_xor(cols_[qt], 32);
  }
  if (quad == 0) {
#pragma unroll
    for (int qt = 0; qt < 4; ++qt) S.colp[w][16 * qt + col] = cols_[qt];
  }
  __syncthreads();
  if (t < S_)
    sum_p[bd * S_ + t] = S.colp[0][t] + S.colp[1][t] + S.colp[2][t] + S.colp[3][t];
}

// ---------------- K1: maxpool-pairs (640) + w^2 (188) + cosM (64), one launch.
__global__ __launch_bounds__(256) void k1(const float* __restrict__ P,
                                          const float* __restrict__ Q,
                                          const float* __restrict__ Wf,
                                          float* __restrict__ w2r,
                                          float* __restrict__ cosM,
                                          float* __restrict__ sum_p,
                                          float* __restrict__ sum_q,
                                          float* __restrict__ out) {
  extern __shared__ char smem[];
  int bid = blockIdx.x;
  if (bid < NB_MP) {
    maxpool_body(smem, bid, P, Q, Wf, out);
  } else if (bid < NB_MP + NB_W) {
    int i = (bid - NB_MP) * 256 + threadIdx.x;
    if (i < 8 * L_ * H_) {
      float v = Wf[i];
      w2r[i] = v * v;
    }
  } else {
    cosm_body(smem, bid - (NB_MP + NB_W), P, Q, cosM, sum_p, sum_q);
  }
}

// ---------------- K2: byte-identical to r16-verified version.
#define SG 4
struct OutsS {                      // 33664 B
  float u[600];                     // cosT (512 floats used)
  float ttq[300], ttp[300];         // dedicated tq/tp (cosT stays live)
  float xP[SG][H_], xQ[SG][H_];
  float vmq[SG][H_], vmp[SG][H_], vxq[SG][H_], vxp[SG][H_];
  float sps[SG], sqs[SG];
};

__device__ __forceinline__ void outs_tail_job(const OutsS& S, int l, int pr,
                                              int si, int dir, int b, int s0,
                                              const float* __restrict__ w2r,
                                              float* __restrict__ out) {
  const float* xv = (pr & 1) ? S.xQ[si] : S.xP[si];
  const float* y;
  if (pr == 0) y = S.ttq;
  else if (pr == 1) y = S.ttp;
  else if (pr == 2) y = S.vmq[si];
  else if (pr == 3) y = S.vmp[si];
  else if (pr == 4) y = S.vxq[si];
  else y = S.vxp[si];
  const int wb_[6] = {0, 0, 4, 4, 6, 6};
  int widx = wb_[pr] + dir;
  const float* wp = w2r + (size_t)widx * (L_ * H_) + (size_t)l * H_;   // row layout
  float4v a1v = {0.f, 0.f, 0.f, 0.f};
  float4v a2v = {0.f, 0.f, 0.f, 0.f};
  float4v a3v = {0.f, 0.f, 0.f, 0.f};
  for (int h4 = 0; h4 < H_; h4 += 4) {
    float4v wv = *(const float4v*)&wp[h4];
    float4v xx = *(const float4v*)&xv[h4];
    float4v yy = *(const float4v*)&y[h4];
    float4v wx = wv * xx;
    float4v wy = wv * yy;
    a1v = wx * yy + a1v;
    a2v = wx * xx + a2v;
    a3v = wy * yy + a3v;
  }
  float a1 = (a1v.x + a1v.y) + (a1v.z + a1v.w);
  float a2 = (a2v.x + a2v.y) + (a2v.z + a2v.w);
  float a3 = (a3v.x + a3v.y) + (a3v.z + a3v.w);
  float den = fmaxf(sqrtf(a2) * sqrtf(a3), 1e-8f);   // EPS per _mp_cos
  float c = a1 / den;
  int s = s0 + si;
  size_t base = ((pr & 1) ? OUTQ_OFF : 0) + ((size_t)b * S_ + s) * ROW_;
  out[base + (size_t)widx * L_ + l] = c;
}

__global__ __launch_bounds__(512) void k2(const float* __restrict__ P,
                                          const float* __restrict__ Q,
                                          const float* __restrict__ w2r,
                                          const float* __restrict__ cosM,
                                          const float* __restrict__ sum_p,
                                          const float* __restrict__ sum_q,
                                          float* __restrict__ out) {
  extern __shared__ char smem[];
  OutsS& S = *(OutsS*)smem;
  int bid = blockIdx.x;
  // XCD swizzle: bd = (bid&7) + 8*((bid>>3)&7); sg = bid>>6
  int x = bid & 7, j = bid >> 3;
  int bd = x + 8 * (j & 7);
  int sg = j >> 3;
  int s0 = sg * SG;
  int b = bd >> 1, dir = bd & 1;
  int t = threadIdx.x;
  int tgt = dir ? 0 : S_ - 1;
  const float* Pb = P + (size_t)b * S_ * H2_ + dir * H_;
  const float* Qb = Q + (size_t)b * S_ * H2_ + dir * H_;
  // ---- phase 0: all staging
  float (*cosT)[8] = (float (*)[8])&S.u[0];     // 512 floats in u[600]
  const float* cm = cosM + (size_t)bd * S_ * S_;
  {
    int k = t >> 3, jj = t & 7, si = jj & 3;    // 512 entries, one per thread
    cosT[k][jj] = (jj < 4) ? cm[(size_t)k * S_ + s0 + si]
                           : cm[(size_t)(s0 + si) * S_ + k];
  }
  if (t < SG * 75) {                            // 300 b128 pairs
    int si = t / 75, c4 = t - si * 75;
    *(float4v*)&S.xP[si][4 * c4] = *(const float4v*)&Pb[(size_t)(s0 + si) * H2_ + 4 * c4];
    *(float4v*)&S.xQ[si][4 * c4] = *(const float4v*)&Qb[(size_t)(s0 + si) * H2_ + 4 * c4];
  } else if (t < 375) {                         // ttq: 75 float4
    int i = t - 300;
    *(float4v*)&S.ttq[4 * i] = *(const float4v*)&Qb[(size_t)tgt * H2_ + 4 * i];
  } else if (t < 450) {                         // ttp: 75 float4
    int i = t - 375;
    *(float4v*)&S.ttp[4 * i] = *(const float4v*)&Pb[(size_t)tgt * H2_ + 4 * i];
  } else if (t < 454) {
    S.sps[t - 450] = sum_p[bd * S_ + s0 + (t - 450)];
  } else if (t < 458) {
    S.sqs[t - 454] = sum_q[bd * S_ + s0 + (t - 454)];
  }
  __syncthreads();
  // ---- phase 1: middle (waves 0-4) CONCURRENT with pr01 tail (waves 5-7)
  if (t < H_) {                                 // middle: h = t
    int h = t;
    float2v amp01 = {0.f, 0.f}, amp23 = {0.f, 0.f};
    float2v amq01 = {0.f, 0.f}, amq23 = {0.f, 0.f};
    float2v axp01 = {NEG_INF, NEG_INF}, axp23 = {NEG_INF, NEG_INF};
    float2v axq01 = {NEG_INF, NEG_INF}, axq23 = {NEG_INF, NEG_INF};
#pragma unroll 4
    for (int k = 0; k < S_; ++k) {
      float pv = Pb[(size_t)k * H2_ + h];
      float qv = Qb[(size_t)k * H2_ + h];
      float4v cc = *(const float4v*)&cosT[k][0];
      float4v cr = *(const float4v*)&cosT[k][4];
      float2v cc01 = {cc.x, cc.y}, cc23 = {cc.z, cc.w};
      float2v cr01 = {cr.x, cr.y}, cr23 = {cr.z, cr.w};
      float2v m0 = pv * cc01;
      amp01 += m0; axp01 = __builtin_elementwise_max(axp01, m0);
      float2v m1 = pv * cc23;
      amp23 += m1; axp23 = __builtin_elementwise_max(axp23, m1);
      float2v m2 = qv * cr01;
      amq01 += m2; axq01 = __builtin_elementwise_max(axq01, m2);
      float2v m3 = qv * cr23;
      amq23 += m3; axq23 = __builtin_elementwise_max(axq23, m3);
    }
    S.vmq[0][h] = amq01.x / S.sqs[0];
    S.vmq[1][h] = amq01.y / S.sqs[1];
    S.vmq[2][h] = amq23.x / S.sqs[2];
    S.vmq[3][h] = amq23.y / S.sqs[3];
    S.vmp[0][h] = amp01.x / S.sps[0];
    S.vmp[1][h] = amp01.y / S.sps[1];
    S.vmp[2][h] = amp23.x / S.sps[2];
    S.vmp[3][h] = amp23.y / S.sps[3];
    S.vxq[0][h] = axq01.x; S.vxq[1][h] = axq01.y;
    S.vxq[2][h] = axq23.x; S.vxq[3][h] = axq23.y;
    S.vxp[0][h] = axp01.x; S.vxp[1][h] = axp01.y;
    S.vxp[2][h] = axp23.x; S.vxp[3][h] = axp23.y;
  } else if (t >= 320 && t < 480) {             // 160 pr01 jobs (middle-indep)
    int jb = t - 320;
    int l = jb >> 3, g = jb & 7;
    int pr = g >> 2, si = g & 3;
    outs_tail_job(S, l, pr, si, dir, b, s0, w2r, out);
  }
  __syncthreads();
  // ---- phase 2: remaining 320 pr2345 jobs
  if (t < 320) {
    int l = t >> 4, g = t & 15;
    int pr = 2 + (g >> 2), si = g & 3;
    outs_tail_job(S, l, pr, si, dir, b, s0, w2r, out);
  }
}

extern "C" void kernel_launch(void* const* d_in, const int* in_sizes, int n_in,
                              void* d_out, int out_size, void* d_ws, size_t ws_size,
                              hipStream_t stream) {
  (void)out_size; (void)ws_size;
  int iw = 2;
  for (int i = 0; i < n_in; ++i) if (in_sizes[i] == 8 * L_ * H_) iw = i;
  int io[2] = {0, 1}, k = 0;
  for (int i = 0; i < n_in && k < 2; ++i) if (i != iw) io[k++] = i;
  const float* P  = (const float*)d_in[io[0]];
  const float* Q  = (const float*)d_in[io[1]];
  const float* Wf = (const float*)d_in[iw];
  float* out = (float*)d_out;

  float* ws = (float*)d_ws;             // ~1.27 MB
  float* w2r     = ws;                  // 48000
  float* cosM    = w2r + 48000;         // 262144
  float* sum_p   = cosM + 262144;       // 4096
  float* sum_q   = sum_p + 4096;        // 4096

  size_t sh1 = sizeof(MaxpoolS);        // 42368 B (CosmS 19968 fits within)
  k1<<<NB_MP + NB_W + NB_CM, 256, sh1, stream>>>(P, Q, Wf, w2r, cosM, sum_p, sum_q, out);
  k2<<<B_ * 2 * 16, 512, sizeof(OutsS), stream>>>(P, Q, w2r, cosM, sum_p, sum_q, out);
}